// Round 11
// baseline (2166.306 us; speedup 1.0000x reference)
//
#include <hip/hip_runtime.h>
#include <math.h>

typedef unsigned short u16;
typedef __attribute__((ext_vector_type(8))) short bf16x8;
typedef __attribute__((ext_vector_type(4))) float f32x4;

// ---- problem dims ----
static constexpr int D_S = 8192;
static constexpr int D_L = 4;
static constexpr int TOK = 65536;
static constexpr float NORMALIZER = 0.4204482076268573f;  // 32^-0.25
static constexpr float RATIO = 0.125f;                    // 64^-0.5
static constexpr float KEPS = 1e-4f;

// ---- workspace layout (float slots) ----
static constexpr size_t OFF_H     = 0;
static constexpr size_t OFF_XNB   = 16777216;
static constexpr size_t OFF_BIG   = 25165824;
static constexpr size_t OFF_V     = 41943040;
static constexpr size_t OFF_WKP   = 46137344;
static constexpr size_t OFF_WQP   = 46268416;
static constexpr size_t OFF_WK    = 46399488;
static constexpr size_t OFF_WQ    = 46465024;
static constexpr size_t OFF_WV    = 46530560;
static constexpr size_t OFF_WO    = 46596096;
static constexpr size_t OFF_W1    = 46661632;
static constexpr size_t OFF_W2    = 46923776;
static constexpr size_t OFF_DG    = 47185920;
static constexpr size_t OFF_KMAX  = 47710208;
static constexpr size_t OFF_PART  = 47710272;
static constexpr size_t OFF_PARTK = 49807424;
static constexpr size_t OFF_CTX   = 49872960;
static constexpr size_t OFF_KSUM  = 50004032;
static constexpr size_t OFF_POOL  = 50008128;
static constexpr size_t NEED_BYTES = 200040704;

static constexpr int BTS = 136;  // Bt row stride in u16 (128 + 8 pad)

static __device__ __forceinline__ float bf2f(u16 u) {
  return __uint_as_float(((unsigned int)u) << 16);
}
static __device__ __forceinline__ u16 f2bf(float f) {
  unsigned int u = __float_as_uint(f);
  u = (u + 0x7fffu + ((u >> 16) & 1u)) >> 16;
  return (u16)u;
}
static __device__ __forceinline__ float geluf(float v) {
  return 0.5f * v * (1.f + erff(v * 0.70710678118654752f));
}
static __device__ __forceinline__ float dec_max(unsigned int mk) {
  return __uint_as_float((mk & 0x80000000u) ? (mk & 0x7fffffffu) : ~mk);
}

// async global->LDS, 16B per lane; dest = wave-uniform base + lane*16 (m97 pattern)
static __device__ __forceinline__ void gload16(const u16* g, u16* l) {
  __builtin_amdgcn_global_load_lds(
      (const __attribute__((address_space(1))) unsigned int*)g,
      (__attribute__((address_space(3))) unsigned int*)l, 16, 0, 0);
}

__global__ void report_kernel(float* out, float v) {
  if (threadIdx.x < 16) out[threadIdx.x] = v;
}

__global__ __launch_bounds__(256) void zero_kernel(float* p, int n) {
  int i = blockIdx.x * 256 + threadIdx.x;
  if (i < n) p[i] = 0.f;
}

// ================= x -> bf16 =================
__global__ __launch_bounds__(256) void xcvt_kernel(const float* __restrict__ x,
                                                   u16* __restrict__ xb) {
  int i4 = (blockIdx.x * 256 + threadIdx.x) * 4;
  float4 v = *(const float4*)(x + i4);
  u16 o[4] = {f2bf(v.x), f2bf(v.y), f2bf(v.z), f2bf(v.w)};
  *(uint2*)(xb + i4) = *(uint2*)o;
}

// ================= layernorm: fp32 in, bf16 out =================
__global__ __launch_bounds__(256) void ln_kernel(
    const float* __restrict__ src, u16* __restrict__ dst,
    const float* __restrict__ g, const float* __restrict__ b) {
  int wv = threadIdx.x >> 6, lane = threadIdx.x & 63;
  int t = blockIdx.x * 4 + wv;
  const float4 v = *(const float4*)(src + (size_t)t * 256 + lane * 4);
  float s1 = v.x + v.y + v.z + v.w;
  float s2 = v.x * v.x + v.y * v.y + v.z * v.z + v.w * v.w;
  for (int off = 32; off; off >>= 1) {
    s1 += __shfl_xor(s1, off);
    s2 += __shfl_xor(s2, off);
  }
  float mu = s1 * (1.f / 256.f);
  float var = s2 * (1.f / 256.f) - mu * mu;
  float rs = rsqrtf(var + 1e-5f);
  float4 gg = *(const float4*)(g + lane * 4);
  float4 bb = *(const float4*)(b + lane * 4);
  u16 o0 = f2bf((v.x - mu) * rs * gg.x + bb.x);
  u16 o1 = f2bf((v.y - mu) * rs * gg.y + bb.y);
  u16 o2 = f2bf((v.z - mu) * rs * gg.z + bb.z);
  u16 o3 = f2bf((v.w - mu) * rs * gg.w + bb.w);
  uint2 pk;
  pk.x = (unsigned)o0 | ((unsigned)o1 << 16);
  pk.y = (unsigned)o2 | ((unsigned)o3 << 16);
  *(uint2*)(dst + (size_t)t * 256 + lane * 4) = pk;
}

// ===== embed weight split (hi/lo), used once pre-loop =====
__global__ __launch_bounds__(256) void wsplit_kernel(
    const float* __restrict__ W, u16* __restrict__ Wt, int K, int N, int nb) {
  int i = blockIdx.x * 256 + threadIdx.x;
  int k = i >> nb, n = i & (N - 1);
  float val = W[i];
  u16 hi = f2bf(val);
  u16 lo = f2bf(val - bf2f(hi));
  Wt[(size_t)n * 2 * K + k] = hi;
  Wt[(size_t)n * 2 * K + K + k] = lo;
}

// ===== merged per-layer weight prep (all single-plane except embed) =====
__global__ __launch_bounds__(256) void wprep_kernel(
    const float* __restrict__ wk, const float* __restrict__ wq,
    const float* __restrict__ wv, const float* __restrict__ wo,
    const float* __restrict__ w1, const float* __restrict__ w2,
    const float* __restrict__ proj,
    u16* __restrict__ WKP, u16* __restrict__ WQP,
    u16* __restrict__ WKt, u16* __restrict__ WQt,
    u16* __restrict__ WVt, u16* __restrict__ WOt,
    u16* __restrict__ W1t, u16* __restrict__ W2t,
    unsigned int* __restrict__ kmaxk) {
  int gi = blockIdx.x * 256 + threadIdx.x;
  if (gi < 64) kmaxk[gi] = 0u;
  if (gi < 262144) {  // WKP / WQP: proj-folded single-plane
    int i = gi & 131071;
    const float* w = (gi < 131072) ? wk : wq;
    u16* Wt = (gi < 131072) ? WKP : WQP;
    int k = i & 255, n = i >> 8;
    int head = n >> 6, m = n & 63;
    float s = 0.f;
#pragma unroll
    for (int d = 0; d < 32; ++d) s += w[k * 256 + head * 32 + d] * proj[m * 32 + d];
    Wt[(size_t)n * 256 + k] = f2bf(s * NORMALIZER);
  } else if (gi < 393216) {  // WKt / WQt single-plane
    int i = gi - 262144;
    const float* W = (i < 65536) ? wk : wq;
    u16* T = (i < 65536) ? WKt : WQt;
    int j = i & 65535;
    int k = j >> 8, n = j & 255;
    T[(size_t)n * 256 + k] = f2bf(W[j]);
  } else if (gi < 524288) {  // WVt / WOt single-plane
    int i = gi - 393216;
    const float* W = (i < 65536) ? wv : wo;
    u16* T = (i < 65536) ? WVt : WOt;
    int j = i & 65535;
    int k = j >> 8, n = j & 255;
    T[(size_t)n * 256 + k] = f2bf(W[j]);
  } else if (gi < 786432) {  // W1 single-plane: K=256, N=1024
    int i = gi - 524288;
    int k = i >> 10, n = i & 1023;
    W1t[(size_t)n * 256 + k] = f2bf(w1[i]);
  } else {                   // W2 single-plane: K=1024, N=256
    int i = gi - 786432;
    int k = i >> 8, n = i & 255;
    W2t[(size_t)n * 1024 + k] = f2bf(w2[i]);
  }
}

// ================= MFMA GEMM: 128x128 tile, A bf16 [M][K], Wt bf16 [N][K*KM] =================
// KM=2: hi/lo split weights; KM=1: single-plane.
// T1 XCD swizzle (bijective), y-fastest -> A-panel L2 reuse per XCD.
// Staging: gload_lds width=16, TRIPLE-buffered counted-vmcnt pipeline (T4, r6/r7 proven):
//   prologue stages 3 bufs (12 in flight); steady iter waits vmcnt(8), computes,
//   raw-barriers, stages t+3. Tail: vmcnt(4) -> vmcnt(0). Never drains mid-loop.
// T5: s_setprio(1) around the MFMA cluster (cross-block arbitration; r10 +17us).
// Chunk swizzle (both-sides, rule 21): LDS slot(row,q') = row*4 + q' holds global k-chunk
// q = q' ^ ((row>>1)&3); fragment reads same XOR -> 2-way bank (free, m136).
// EPI: 0 plain (ACT gelu, ACC fp32-acc, OBF bf16 store), 3 qp, 4 embed,
//      6 fused xp(y<4: store+max over Wt)+diag(y>=4: over Wt2)
template <int EPI, int ACT, int ACC, int OBF, int KM>
__global__ __launch_bounds__(256) void mfma_gemm(
    const u16* __restrict__ A, const u16* __restrict__ Wt,
    const u16* __restrict__ Wt2,
    const float* __restrict__ bias, const float* __restrict__ posP,
    const u16* __restrict__ diagIn,
    float* __restrict__ outF, u16* __restrict__ outB,
    u16* __restrict__ diagOut, unsigned int* __restrict__ kmaxOut,
    int N, int K) {
  __shared__ __align__(16) u16 Als[12288];  // 3 bufs x 512 slots x 8 u16 (24KB)
  __shared__ __align__(16) u16 Bls[12288];
  const int K2 = K * KM;
  int tid = threadIdx.x;
  // ---- T1 bijective XCD swizzle, y-fastest work order ----
  int tot = gridDim.x * gridDim.y;
  int f = blockIdx.x + gridDim.x * blockIdx.y;
  int wid = (f & 7) * (tot >> 3) + (f >> 3);
  int ny = gridDim.y;                       // power of 2 (2,4,8)
  int lg = 31 - __clz(ny);
  int xb = wid >> lg;
  int yb = wid & (ny - 1);
  int bm = xb * 128;
  const u16* Wp = Wt;
  int bn = yb * 128;
  if (EPI == 6 && yb >= 4) { Wp = Wt2; bn = (yb - 4) * 128; }
  int w = tid >> 6, lane = tid & 63;
  int wm = w >> 1, wn = w & 1;
  int lr = lane & 15, lq = lane >> 4;
  f32x4 acc[4][4];
#pragma unroll
  for (int i = 0; i < 4; ++i)
#pragma unroll
    for (int j = 0; j < 4; ++j) acc[i][j] = (f32x4){0.f, 0.f, 0.f, 0.f};
  // staging lane geometry (see header comment)
  int sub = lane >> 2;                         // row within 16-row group
  int qsw = (lane & 3) ^ ((lane >> 3) & 3);    // global k-chunk this lane fetches
  const u16* gA0 = A + (size_t)(bm + 32 * w + sub) * K + qsw * 8;
  const u16* gA1 = gA0 + (size_t)16 * K;
  const u16* gB0 = Wp + (size_t)(bn + 32 * w + sub) * K2 + qsw * 8;
  const u16* gB1 = gB0 + (size_t)16 * K2;
  u16* lA0 = Als + (w * 2 + 0) * 512;          // wave-uniform LDS bases (slot*8 u16)
  u16* lA1 = Als + (w * 2 + 1) * 512;
  u16* lB0 = Bls + (w * 2 + 0) * 512;
  u16* lB1 = Bls + (w * 2 + 1) * 512;
  // fragment read base (chunk swizzle folded in; per-lane constant)
  int qswr = lq ^ ((lr >> 1) & 3);
  int aB = wm * 256 + lr * 4 + qswr;
  int bB = wn * 256 + lr * 4 + qswr;

#define STAGE(buf, kk) do { \
    int ka_ = (kk) & (K - 1); int kb_ = (kk); int lo_ = (buf) * 4096; \
    gload16(gA0 + ka_, lA0 + lo_); \
    gload16(gA1 + ka_, lA1 + lo_); \
    gload16(gB0 + kb_, lB0 + lo_); \
    gload16(gB1 + kb_, lB1 + lo_); \
  } while (0)

  const int nt = K2 / 32;                      // >= 4 for all instantiations
  STAGE(0, 0);
  STAGE(1, 32);
  STAGE(2, 64);
  int cur = 0;
  for (int t = 0; t < nt; ++t) {
    if (t + 2 < nt)      asm volatile("s_waitcnt vmcnt(8)" ::: "memory");
    else if (t + 1 < nt) asm volatile("s_waitcnt vmcnt(4)" ::: "memory");
    else                 asm volatile("s_waitcnt vmcnt(0)" ::: "memory");
    __builtin_amdgcn_s_barrier();              // all waves' cur-buf loads landed
    __builtin_amdgcn_sched_barrier(0);         // pin: no ds_read above barrier1
    const bf16x8* Ab = (const bf16x8*)(Als + cur * 4096);
    const bf16x8* Bb = (const bf16x8*)(Bls + cur * 4096);
    bf16x8 af[4], bfr[4];
#pragma unroll
    for (int mi = 0; mi < 4; ++mi) af[mi] = Ab[aB + mi * 64];
#pragma unroll
    for (int ni = 0; ni < 4; ++ni) bfr[ni] = Bb[bB + ni * 64];
    __builtin_amdgcn_s_setprio(1);             // T5: favor MFMA-entering waves
#pragma unroll
    for (int mi = 0; mi < 4; ++mi)
#pragma unroll
      for (int ni = 0; ni < 4; ++ni)
        acc[mi][ni] = __builtin_amdgcn_mfma_f32_16x16x32_bf16(af[mi], bfr[ni], acc[mi][ni], 0, 0, 0);
    __builtin_amdgcn_s_setprio(0);
    asm volatile("s_waitcnt lgkmcnt(0)" ::: "memory");  // my ds_reads complete
    __builtin_amdgcn_sched_barrier(0);
    __builtin_amdgcn_s_barrier();              // all waves done reading cur buf
    __builtin_amdgcn_sched_barrier(0);         // pin: STAGE stays below barrier2
    if (t + 3 < nt) STAGE(cur, (t + 3) * 32);
    cur = (cur == 2) ? 0 : cur + 1;
  }
#undef STAGE
  // ---- epilogues ----  C/D: col = lane&15, row = (lane>>4)*4 + r  [m89-verified]
  if (EPI == 0) {
#pragma unroll
    for (int ni = 0; ni < 4; ++ni) {
      int col = bn + wn * 64 + ni * 16 + lr;
      float bv = bias ? bias[col] : 0.f;
#pragma unroll
      for (int mi = 0; mi < 4; ++mi)
#pragma unroll
        for (int rr = 0; rr < 4; ++rr) {
          int rowg = bm + wm * 64 + mi * 16 + lq * 4 + rr;
          float val = acc[mi][ni][rr] + bv;
          if (ACT) val = geluf(val);
          size_t o = (size_t)rowg * N + col;
          if (OBF) outB[o] = f2bf(val);
          else if (ACC) outF[o] += val;
          else outF[o] = val;
        }
    }
  }
  if (EPI == 3) {  // qp: in-wave row-max over the head's 64 cols, then exp; dg q-heads at +8
    int head = (bn + wn * 64) >> 6;
#pragma unroll
    for (int mi = 0; mi < 4; ++mi) {
      float rm[4] = {-3.4e38f, -3.4e38f, -3.4e38f, -3.4e38f};
#pragma unroll
      for (int ni = 0; ni < 4; ++ni)
#pragma unroll
        for (int rr = 0; rr < 4; ++rr) rm[rr] = fmaxf(rm[rr], acc[mi][ni][rr]);
#pragma unroll
      for (int rr = 0; rr < 4; ++rr) {
        float t = rm[rr];
        t = fmaxf(t, __shfl_xor(t, 1)); t = fmaxf(t, __shfl_xor(t, 2));
        t = fmaxf(t, __shfl_xor(t, 4)); t = fmaxf(t, __shfl_xor(t, 8));
        rm[rr] = t;
      }
#pragma unroll
      for (int rr = 0; rr < 4; ++rr) {
        int rowg = bm + wm * 64 + mi * 16 + lq * 4 + rr;
        float dgv = bf2f(diagIn[(size_t)rowg * 16 + 8 + head]);
#pragma unroll
        for (int ni = 0; ni < 4; ++ni) {
          int col = bn + wn * 64 + ni * 16 + lr;
          float v = RATIO * (__expf(acc[mi][ni][rr] - dgv - rm[rr]) + KEPS);
          outB[(size_t)rowg * N + col] = f2bf(v);
        }
      }
    }
  }
  if (EPI == 4) {  // embed: + bias + pos, fp32 store (N==256)
#pragma unroll
    for (int ni = 0; ni < 4; ++ni) {
      int col = bn + wn * 64 + ni * 16 + lr;
      float bv = bias[col];
#pragma unroll
      for (int mi = 0; mi < 4; ++mi)
#pragma unroll
        for (int rr = 0; rr < 4; ++rr) {
          int rowg = bm + wm * 64 + mi * 16 + lq * 4 + rr;
          outF[(size_t)rowg * 256 + col] =
              acc[mi][ni][rr] + bv + posP[(size_t)(rowg & (D_S - 1)) * 256 + col];
        }
    }
  }
  if (EPI == 6) {
    if (yb < 4) {  // xp: store bf16 + global max per (b, head)
      float mx = -3.4e38f;
#pragma unroll
      for (int mi = 0; mi < 4; ++mi)
#pragma unroll
        for (int ni = 0; ni < 4; ++ni)
#pragma unroll
          for (int rr = 0; rr < 4; ++rr) {
            float v = acc[mi][ni][rr];
            mx = fmaxf(mx, v);
            int rowg = bm + wm * 64 + mi * 16 + lq * 4 + rr;
            int col = bn + wn * 64 + ni * 16 + lr;
            outB[(size_t)rowg * N + col] = f2bf(v);
          }
#pragma unroll
      for (int off = 1; off < 64; off <<= 1) mx = fmaxf(mx, __shfl_xor(mx, off));
      if (lane == 0) {
        int b = bm >> 13;
        int head = (bn + wn * 64) >> 6;
        unsigned int u = __float_as_uint(mx);
        unsigned int key = (u & 0x80000000u) ? ~u : (u | 0x80000000u);
        atomicMax(kmaxOut + b * 8 + head, key);
      }
    } else {  // diag per head (32 cols); wave spans 2 heads; dg layout [t][16]
      const float c05n2 = 0.5f * NORMALIZER * NORMALIZER;
      int hb = (bn + wn * 64) >> 5;
#pragma unroll
      for (int mi = 0; mi < 4; ++mi) {
        float s0[4] = {0.f, 0.f, 0.f, 0.f}, s1[4] = {0.f, 0.f, 0.f, 0.f};
#pragma unroll
        for (int ni = 0; ni < 4; ++ni)
#pragma unroll
          for (int rr = 0; rr < 4; ++rr) {
            float v = acc[mi][ni][rr];
            if (ni < 2) s0[rr] += v * v; else s1[rr] += v * v;
          }
#pragma unroll
        for (int rr = 0; rr < 4; ++rr) {
          float a = s0[rr], b = s1[rr];
          a += __shfl_xor(a, 1); a += __shfl_xor(a, 2); a += __shfl_xor(a, 4); a += __shfl_xor(a, 8);
          b += __shfl_xor(b, 1); b += __shfl_xor(b, 2); b += __shfl_xor(b, 4); b += __shfl_xor(b, 8);
          if (lr == 0) {
            int rowg = bm + wm * 64 + mi * 16 + lq * 4 + rr;
            diagOut[(size_t)rowg * 16 + hb] = f2bf(c05n2 * a);
            diagOut[(size_t)rowg * 16 + hb + 1] = f2bf(c05n2 * b);
          }
        }
      }
    }
  }
}

// ===== ctxaccum: kp computed inline from raw xp (exp fused); part[m][e] = sum kp*v =====
// r11: m-split across 2x blocks (grid 64x16): each block owns 32 of 64 random features
// (own exp columns, no duplicate exp), LDS 24KB->16KB, occupancy 2->4 blocks/CU.
__global__ __launch_bounds__(256) void ctxaccum_kernel(
    const u16* __restrict__ xp, const u16* __restrict__ v,
    const u16* __restrict__ dg, const unsigned int* __restrict__ kmaxk,
    float* __restrict__ part, float* __restrict__ partk, int hf) {
  __shared__ float kpS[64 * 32];
  __shared__ float vS[64 * 32];
  int tid = threadIdx.x;
  int bx = blockIdx.x;                    // 64 = (bl*8+head)*2 + mh
  int mh = bx & 1;
  int bh32 = bx >> 1;
  int bl = bh32 >> 3, head = bh32 & 7, c = blockIdx.y;
  int n0l = bl * 8192 + c * 512;          // within half (32768 tokens)
  int bhg = (hf * 4 + bl) * 8 + head;
  int tg0 = hf * 32768 + n0l;
  float mx = dec_max(kmaxk[bhg]);
  int m = tid & 31, eg = tid >> 5;        // m' 0..31, eg 0..7 (e = eg*4..+3)
  int mg = mh * 32 + m;                   // global m 0..63
  float acc[4] = {};
  float ks = 0.f;
  const u16* kpb = xp + (size_t)tg0 * 512 + head * 64 + mh * 32;
  const u16* vb = v + (size_t)n0l * 256 + head * 32;
  for (int tile = 0; tile < 8; ++tile) {
    int nb = tile * 64;
    __syncthreads();
    {
      int row = tid >> 2, c8 = (tid & 3) * 8;   // 64 rows x 32 m-cols, 8 each
      float dgrow = bf2f(dg[(size_t)(tg0 + nb + row) * 16 + head]);
      u16 tmp[8];
      *(uint4*)tmp = *(const uint4*)(kpb + (size_t)(nb + row) * 512 + c8);
#pragma unroll
      for (int j = 0; j < 8; ++j)
        kpS[row * 32 + c8 + j] = RATIO * (__expf(bf2f(tmp[j]) - dgrow - mx) + KEPS);
    }
    {
      int row = tid >> 2, c8 = (tid & 3) * 8;
      u16 tmp[8];
      *(uint4*)tmp = *(const uint4*)(vb + (size_t)(nb + row) * 256 + c8);
#pragma unroll
      for (int j = 0; j < 8; ++j) vS[row * 32 + c8 + j] = bf2f(tmp[j]);
    }
    __syncthreads();
#pragma unroll 4
    for (int n = 0; n < 64; ++n) {
      float kv = kpS[n * 32 + m];
      if (eg == 0) ks += kv;
      const float* vr = &vS[n * 32 + eg * 4];
#pragma unroll
      for (int j = 0; j < 4; ++j) acc[j] += kv * vr[j];
    }
  }
  float* pp = part + ((size_t)bhg * 16 + c) * 2048 + mg * 32 + eg * 4;
#pragma unroll
  for (int j = 0; j < 4; ++j) pp[j] = acc[j];
  if (eg == 0) partk[((size_t)bhg * 16 + c) * 64 + mg] = ks;
}

__global__ __launch_bounds__(256) void ctxreduce_kernel(
    const float* __restrict__ part, const float* __restrict__ partk,
    float* __restrict__ ctx, float* __restrict__ ksum) {
  int bh = blockIdx.x, tid = threadIdx.x;
#pragma unroll
  for (int i = 0; i < 8; ++i) {
    int idx = tid + i * 256;
    float s = 0.f;
#pragma unroll
    for (int cc = 0; cc < 16; ++cc)
      s += part[((size_t)bh * 16 + cc) * 2048 + idx];
    ctx[(size_t)bh * 2048 + idx] = s;
  }
  if (tid < 64) {
    float s = 0.f;
#pragma unroll
    for (int cc = 0; cc < 16; ++cc) s += partk[((size_t)bh * 16 + cc) * 64 + tid];
    ksum[bh * 64 + tid] = s;
  }
}

// ===== btprep: pack [ctx | ksum | 0] into B-operand hi/lo bf16: Bt[bh][48][BTS] =====
__global__ __launch_bounds__(256) void btprep_kernel(
    const float* __restrict__ ctx, const float* __restrict__ ksum,
    u16* __restrict__ Bt) {
  int bh = blockIdx.x, tid = threadIdx.x;
  for (int idx = tid; idx < 48 * 64; idx += 256) {
    int n = idx >> 6, k = idx & 63;
    float v = 0.f;
    if (n < 32) v = ctx[(size_t)bh * 2048 + k * 32 + n];
    else if (n == 32) v = ksum[bh * 64 + k];
    u16 hi = f2bf(v);
    u16 lo = f2bf(v - bf2f(hi));
    u16* row = Bt + ((size_t)bh * 48 + n) * BTS;
    row[k] = hi;
    row[64 + k] = lo;
  }
}

// ===== attnout via MFMA: ao = (qp@ctx)/(qp@ksum) =====
__global__ __launch_bounds__(256) void attnout_kernel(
    const u16* __restrict__ qp, const u16* __restrict__ Bt,
    u16* __restrict__ ao, int hf) {
  __shared__ __align__(16) u16 BtS[48 * BTS];
  int tid = threadIdx.x;
  int rb = blockIdx.x, head = blockIdx.y;
  int t0l = rb * 128;
  int bhg = ((hf * 32768 + t0l) >> 13) * 8 + head;
  {
    const uint4* src = (const uint4*)(Bt + (size_t)bhg * 48 * BTS);
    for (int i = tid; i < 48 * BTS / 8; i += 256) ((uint4*)BtS)[i] = src[i];
  }
  __syncthreads();
  int w = tid >> 6, lane = tid & 63;
  int lr = lane & 15, lq = lane >> 4;
  int tw = t0l + w * 32;
  const u16* qpb = qp + (size_t)(hf * 32768 + tw) * 512 + head * 64;
  bf16x8 af[2][2];
#pragma unroll
  for (int mt = 0; mt < 2; ++mt)
#pragma unroll
    for (int kc = 0; kc < 2; ++kc)
      af[mt][kc] = *(const bf16x8*)(qpb + (size_t)(mt * 16 + lr) * 512 + kc * 32 + lq * 8);
  f32x4 c0[2], c1[2], c2[2];
#pragma unroll
  for (int mt = 0; mt < 2; ++mt) {
    c0[mt] = (f32x4){0.f, 0.f, 0.f, 0.f};
    c1[mt] = (f32x4){0.f, 0.f, 0.f, 0.f};
    c2[mt] = (f32x4){0.f, 0.f, 0.f, 0.f};
  }
  __builtin_amdgcn_s_setprio(1);               // T5 (attn-positive, m191)
#pragma unroll
  for (int kc = 0; kc < 4; ++kc) {
    bf16x8 b0 = *(const bf16x8*)(BtS + (size_t)(0 * 16 + lr) * BTS + kc * 32 + lq * 8);
    bf16x8 b1 = *(const bf16x8*)(BtS + (size_t)(1 * 16 + lr) * BTS + kc * 32 + lq * 8);
    bf16x8 b2 = *(const bf16x8*)(BtS + (size_t)(2 * 16 + lr) * BTS + kc * 32 + lq * 8);
#pragma unroll
    for (int mt = 0; mt < 2; ++mt) {
      bf16x8 a = af[mt][kc & 1];
      c0[mt] = __builtin_amdgcn_mfma_f32_16x16x32_bf16(a, b0, c0[mt], 0, 0, 0);
      c1[mt] = __builtin_amdgcn_mfma_f32_16x16x32_bf16(a, b1, c1[mt], 0, 0, 0);
      c2[mt] = __builtin_amdgcn_mfma_f32_16x16x32_bf16(a, b2, c2[mt], 0, 0, 0);
    }
  }
  __builtin_amdgcn_s_setprio(0);
#pragma unroll
  for (int mt = 0; mt < 2; ++mt)
#pragma unroll
    for (int rr = 0; rr < 4; ++rr) {
      float den = __shfl(c2[mt][rr], lane & 48);
      int rowl = tw + mt * 16 + lq * 4 + rr;
      float inv = 1.f / den;
      ao[(size_t)rowl * 256 + head * 32 + lr] = f2bf(c0[mt][rr] * inv);
      ao[(size_t)rowl * 256 + head * 32 + 16 + lr] = f2bf(c1[mt][rr] * inv);
    }
}

// ================= mean pool + final FC (fp32 h) =================
__global__ __launch_bounds__(256) void pool_kernel(
    const float* __restrict__ h, float* __restrict__ pooled) {
  int b = blockIdx.x, chunk = blockIdx.y, j = threadIdx.x;
  const float* hp = h + (size_t)(b * D_S + chunk * 256) * 256 + j;
  float acc = 0.f;
#pragma unroll 4
  for (int s = 0; s < 256; ++s) acc += hp[(size_t)s * 256];
  atomicAdd(pooled + b * 256 + j, acc);
}

__global__ __launch_bounds__(64) void final_kernel(
    const float* __restrict__ pooled, const float* __restrict__ fcw,
    const float* __restrict__ fcb, float* __restrict__ out) {
  int tid = threadIdx.x;
  if (tid >= 16) return;
  int b = tid >> 1, c = tid & 1;
  float acc = 0.f;
  for (int j = 0; j < 256; ++j) acc += pooled[b * 256 + j] * fcw[j * 2 + c];
  out[b * 2 + c] = acc * (1.f / 8192.f) + fcb[c];
}

extern "C" void kernel_launch(void* const* d_in, const int* in_sizes, int n_in,
                              void* d_out, int out_size, void* d_ws, size_t ws_size,
                              hipStream_t stream) {
  const float* x     = (const float*)d_in[0];
  const float* emb_w = (const float*)d_in[1];
  const float* emb_b = (const float*)d_in[2];
  const float* pos   = (const float*)d_in[3];
  const float* ln1_g = (const float*)d_in[4];
  const float* ln1_b = (const float*)d_in[5];
  const float* wq    = (const float*)d_in[6];
  const float* wk    = (const float*)d_in[7];
  const float* wv    = (const float*)d_in[8];
  const float* wo    = (const float*)d_in[9];
  const float* bo    = (const float*)d_in[10];
  const float* ln2_g = (const float*)d_in[11];
  const float* ln2_b = (const float*)d_in[12];
  const float* w1    = (const float*)d_in[13];
  const float* b1    = (const float*)d_in[14];
  const float* w2    = (const float*)d_in[15];
  const float* b2    = (const float*)d_in[16];
  const float* proj  = (const float*)d_in[17];
  const float* fc_w  = (const float*)d_in[18];
  const float* fc_b  = (const float*)d_in[19];

  if (ws_size < NEED_BYTES) {
    report_kernel<<<1, 64, 0, stream>>>((float*)d_out, (float)ws_size);
    return;
  }

  float* ws = (float*)d_ws;
  float* h      = ws + OFF_H;
  u16* xnb      = (u16*)(ws + OFF_XNB);
  u16* BIG      = (u16*)(ws + OFF_BIG);
  u16* Vb       = (u16*)(ws + OFF_V);
  u16* WKPt     = (u16*)(ws + OFF_WKP);
  u16* WQPt     = (u16*)(ws + OFF_WQP);
  u16* WKt      = (u16*)(ws + OFF_WK);
  u16* WQt      = (u16*)(ws + OFF_WQ);
  u16* WVt      = (u16*)(ws + OFF_WV);
  u16* WOt      = (u16*)(ws + OFF_WO);
  u16* W1t      = (u16*)(ws + OFF_W1);
  u16* W2t      = (u16*)(ws + OFF_W2);
  u16* dg       = (u16*)(ws + OFF_DG);
  unsigned int* kmaxk = (unsigned int*)(ws + OFF_KMAX);
  float* part   = ws + OFF_PART;
  u16* Bt       = (u16*)(ws + OFF_PART);  // reuses part after ctxreduce (btprep reads ctx/ksum only)
  float* partk  = ws + OFF_PARTK;
  float* ctx    = ws + OFF_CTX;
  float* ksum   = ws + OFF_KSUM;
  float* pooled = ws + OFF_POOL;

  // ---- embed as MFMA GEMM ----
  xcvt_kernel<<<4096, 256, 0, stream>>>(x, BIG);
  wsplit_kernel<<<64, 256, 0, stream>>>(emb_w, WKPt, 64, 256, 8);
  mfma_gemm<4, 0, 0, 0, 2><<<dim3(512, 2), 256, 0, stream>>>(
      BIG, WKPt, nullptr, emb_b, pos, nullptr, h, nullptr, nullptr, nullptr, 256, 64);

  for (int l = 0; l < D_L; ++l) {
    const float* pj = proj + l * 2048;
    ln_kernel<<<TOK / 4, 256, 0, stream>>>(h, xnb, ln1_g + l * 256, ln1_b + l * 256);
    wprep_kernel<<<4096, 256, 0, stream>>>(
        wk + l * 65536, wq + l * 65536, wv + l * 65536, wo + l * 65536,
        w1 + l * 262144, w2 + l * 262144, pj,
        WKPt, WQPt, WKt, WQt, WVt, WOt, W1t, W2t, kmaxk);

    // fused xp(+kmax) and diag(k|q): one launch, y<4 xp / y>=4 diag
    mfma_gemm<6, 0, 0, 1, 1><<<dim3(512, 8), 256, 0, stream>>>(
        xnb, WKPt, WKt, nullptr, nullptr, nullptr, nullptr, BIG, dg, kmaxk, 512, 256);
    // context accumulation per half (exp fused into staging; m-split grid)
    for (int hf = 0; hf < 2; ++hf) {
      const u16* xh = xnb + (size_t)hf * 32768 * 256;
      mfma_gemm<0, 0, 0, 1, 1><<<dim3(256, 2), 256, 0, stream>>>(
          xh, WVt, nullptr, nullptr, nullptr, nullptr, nullptr, Vb, nullptr, nullptr, 256, 256);
      ctxaccum_kernel<<<dim3(64, 16), 256, 0, stream>>>(BIG, Vb, dg, kmaxk, part, partk, hf);
    }
    ctxreduce_kernel<<<64, 256, 0, stream>>>(part, partk, ctx, ksum);
    btprep_kernel<<<64, 256, 0, stream>>>(ctx, ksum, Bt);
    // qp (overwrites BIG; xp dead), single-plane WQP
    mfma_gemm<3, 0, 0, 1, 1><<<dim3(512, 4), 256, 0, stream>>>(
        xnb, WQPt, nullptr, nullptr, nullptr, dg, nullptr, BIG, nullptr, nullptr, 512, 256);
    for (int hf = 0; hf < 2; ++hf) {
      float* hh = h + (size_t)hf * 32768 * 256;
      attnout_kernel<<<dim3(256, 8), 256, 0, stream>>>(BIG, Bt, Vb, hf);
      mfma_gemm<0, 0, 1, 0, 1><<<dim3(256, 2), 256, 0, stream>>>(
          Vb, WOt, nullptr, bo + l * 256, nullptr, nullptr, hh, nullptr, nullptr, nullptr, 256, 256);
    }

    ln_kernel<<<TOK / 4, 256, 0, stream>>>(h, xnb, ln2_g + l * 256, ln2_b + l * 256);
    for (int hf = 0; hf < 2; ++hf) {
      const u16* xh = xnb + (size_t)hf * 32768 * 256;
      float* hh = h + (size_t)hf * 32768 * 256;
      // FFN single-plane bf16 (KM=1)
      mfma_gemm<0, 1, 0, 1, 1><<<dim3(256, 8), 256, 0, stream>>>(
          xh, W1t, nullptr, b1 + l * 1024, nullptr, nullptr, nullptr, BIG, nullptr, nullptr, 1024, 256);
      mfma_gemm<0, 0, 1, 0, 1><<<dim3(256, 2), 256, 0, stream>>>(
          BIG, W2t, nullptr, b2 + l * 256, nullptr, nullptr, hh, nullptr, nullptr, nullptr, 256, 1024);
    }
  }

  zero_kernel<<<8, 256, 0, stream>>>(pooled, 2048);
  pool_kernel<<<dim3(8, 32), 256, 0, stream>>>(h, pooled);
  final_kernel<<<1, 64, 0, stream>>>(pooled, fc_w, fc_b, (float*)d_out);
}

// Round 12
// 2160.136 us; speedup vs baseline: 1.0029x; 1.0029x over previous
//
#include <hip/hip_runtime.h>
#include <math.h>

typedef unsigned short u16;
typedef __attribute__((ext_vector_type(8))) short bf16x8;
typedef __attribute__((ext_vector_type(4))) float f32x4;

// ---- problem dims ----
static constexpr int D_S = 8192;
static constexpr int D_L = 4;
static constexpr int TOK = 65536;
static constexpr float NORMALIZER = 0.4204482076268573f;  // 32^-0.25
static constexpr float RATIO = 0.125f;                    // 64^-0.5
static constexpr float KEPS = 1e-4f;

// ---- workspace layout (float slots) ----
static constexpr size_t OFF_H     = 0;
static constexpr size_t OFF_XNB   = 16777216;
static constexpr size_t OFF_BIG   = 25165824;
static constexpr size_t OFF_V     = 41943040;
static constexpr size_t OFF_WKP   = 46137344;
static constexpr size_t OFF_WQP   = 46268416;
static constexpr size_t OFF_WK    = 46399488;
static constexpr size_t OFF_WQ    = 46465024;
static constexpr size_t OFF_WV    = 46530560;
static constexpr size_t OFF_WO    = 46596096;
static constexpr size_t OFF_W1    = 46661632;
static constexpr size_t OFF_W2    = 46923776;
static constexpr size_t OFF_DG    = 47185920;
static constexpr size_t OFF_KMAX  = 47710208;
static constexpr size_t OFF_PART  = 47710272;
static constexpr size_t OFF_PARTK = 49807424;
static constexpr size_t OFF_CTX   = 49872960;
static constexpr size_t OFF_KSUM  = 50004032;
static constexpr size_t OFF_POOL  = 50008128;
static constexpr size_t NEED_BYTES = 200040704;

static constexpr int BTS = 136;  // Bt row stride in u16 (128 + 8 pad)

static __device__ __forceinline__ float bf2f(u16 u) {
  return __uint_as_float(((unsigned int)u) << 16);
}
static __device__ __forceinline__ u16 f2bf(float f) {
  unsigned int u = __float_as_uint(f);
  u = (u + 0x7fffu + ((u >> 16) & 1u)) >> 16;
  return (u16)u;
}
static __device__ __forceinline__ float geluf(float v) {
  return 0.5f * v * (1.f + erff(v * 0.70710678118654752f));
}
static __device__ __forceinline__ float dec_max(unsigned int mk) {
  return __uint_as_float((mk & 0x80000000u) ? (mk & 0x7fffffffu) : ~mk);
}

// async global->LDS, 16B per lane; dest = wave-uniform base + lane*16 (m97 pattern)
static __device__ __forceinline__ void gload16(const u16* g, u16* l) {
  __builtin_amdgcn_global_load_lds(
      (const __attribute__((address_space(1))) unsigned int*)g,
      (__attribute__((address_space(3))) unsigned int*)l, 16, 0, 0);
}

__global__ void report_kernel(float* out, float v) {
  if (threadIdx.x < 16) out[threadIdx.x] = v;
}

__global__ __launch_bounds__(256) void zero_kernel(float* p, int n) {
  int i = blockIdx.x * 256 + threadIdx.x;
  if (i < n) p[i] = 0.f;
}

// ================= x -> bf16 =================
__global__ __launch_bounds__(256) void xcvt_kernel(const float* __restrict__ x,
                                                   u16* __restrict__ xb) {
  int i4 = (blockIdx.x * 256 + threadIdx.x) * 4;
  float4 v = *(const float4*)(x + i4);
  u16 o[4] = {f2bf(v.x), f2bf(v.y), f2bf(v.z), f2bf(v.w)};
  *(uint2*)(xb + i4) = *(uint2*)o;
}

// ================= layernorm: fp32 in, bf16 out =================
__global__ __launch_bounds__(256) void ln_kernel(
    const float* __restrict__ src, u16* __restrict__ dst,
    const float* __restrict__ g, const float* __restrict__ b) {
  int wv = threadIdx.x >> 6, lane = threadIdx.x & 63;
  int t = blockIdx.x * 4 + wv;
  const float4 v = *(const float4*)(src + (size_t)t * 256 + lane * 4);
  float s1 = v.x + v.y + v.z + v.w;
  float s2 = v.x * v.x + v.y * v.y + v.z * v.z + v.w * v.w;
  for (int off = 32; off; off >>= 1) {
    s1 += __shfl_xor(s1, off);
    s2 += __shfl_xor(s2, off);
  }
  float mu = s1 * (1.f / 256.f);
  float var = s2 * (1.f / 256.f) - mu * mu;
  float rs = rsqrtf(var + 1e-5f);
  float4 gg = *(const float4*)(g + lane * 4);
  float4 bb = *(const float4*)(b + lane * 4);
  u16 o0 = f2bf((v.x - mu) * rs * gg.x + bb.x);
  u16 o1 = f2bf((v.y - mu) * rs * gg.y + bb.y);
  u16 o2 = f2bf((v.z - mu) * rs * gg.z + bb.z);
  u16 o3 = f2bf((v.w - mu) * rs * gg.w + bb.w);
  uint2 pk;
  pk.x = (unsigned)o0 | ((unsigned)o1 << 16);
  pk.y = (unsigned)o2 | ((unsigned)o3 << 16);
  *(uint2*)(dst + (size_t)t * 256 + lane * 4) = pk;
}

// ===== embed weight split (hi/lo), used once pre-loop =====
__global__ __launch_bounds__(256) void wsplit_kernel(
    const float* __restrict__ W, u16* __restrict__ Wt, int K, int N, int nb) {
  int i = blockIdx.x * 256 + threadIdx.x;
  int k = i >> nb, n = i & (N - 1);
  float val = W[i];
  u16 hi = f2bf(val);
  u16 lo = f2bf(val - bf2f(hi));
  Wt[(size_t)n * 2 * K + k] = hi;
  Wt[(size_t)n * 2 * K + K + k] = lo;
}

// ===== merged per-layer weight prep (all single-plane except embed) =====
__global__ __launch_bounds__(256) void wprep_kernel(
    const float* __restrict__ wk, const float* __restrict__ wq,
    const float* __restrict__ wv, const float* __restrict__ wo,
    const float* __restrict__ w1, const float* __restrict__ w2,
    const float* __restrict__ proj,
    u16* __restrict__ WKP, u16* __restrict__ WQP,
    u16* __restrict__ WKt, u16* __restrict__ WQt,
    u16* __restrict__ WVt, u16* __restrict__ WOt,
    u16* __restrict__ W1t, u16* __restrict__ W2t,
    unsigned int* __restrict__ kmaxk) {
  int gi = blockIdx.x * 256 + threadIdx.x;
  if (gi < 64) kmaxk[gi] = 0u;
  if (gi < 262144) {  // WKP / WQP: proj-folded single-plane
    int i = gi & 131071;
    const float* w = (gi < 131072) ? wk : wq;
    u16* Wt = (gi < 131072) ? WKP : WQP;
    int k = i & 255, n = i >> 8;
    int head = n >> 6, m = n & 63;
    float s = 0.f;
#pragma unroll
    for (int d = 0; d < 32; ++d) s += w[k * 256 + head * 32 + d] * proj[m * 32 + d];
    Wt[(size_t)n * 256 + k] = f2bf(s * NORMALIZER);
  } else if (gi < 393216) {  // WKt / WQt single-plane
    int i = gi - 262144;
    const float* W = (i < 65536) ? wk : wq;
    u16* T = (i < 65536) ? WKt : WQt;
    int j = i & 65535;
    int k = j >> 8, n = j & 255;
    T[(size_t)n * 256 + k] = f2bf(W[j]);
  } else if (gi < 524288) {  // WVt / WOt single-plane
    int i = gi - 393216;
    const float* W = (i < 65536) ? wv : wo;
    u16* T = (i < 65536) ? WVt : WOt;
    int j = i & 65535;
    int k = j >> 8, n = j & 255;
    T[(size_t)n * 256 + k] = f2bf(W[j]);
  } else if (gi < 786432) {  // W1 single-plane: K=256, N=1024
    int i = gi - 524288;
    int k = i >> 10, n = i & 1023;
    W1t[(size_t)n * 256 + k] = f2bf(w1[i]);
  } else {                   // W2 single-plane: K=1024, N=256
    int i = gi - 786432;
    int k = i >> 8, n = i & 255;
    W2t[(size_t)n * 1024 + k] = f2bf(w2[i]);
  }
}

// ================= MFMA GEMM: 128x128 tile, A bf16 [M][K], Wt bf16 [N][K*KM] =================
// KM=2: hi/lo split weights; KM=1: single-plane.
// T1 XCD swizzle (bijective), y-fastest -> A-panel L2 reuse per XCD.
// Staging: gload_lds width=16, TRIPLE-buffered counted-vmcnt pipeline (T4, r6/r7 proven):
//   prologue stages 3 bufs (12 in flight); steady iter waits vmcnt(8), computes,
//   raw-barriers, stages t+3. Tail: vmcnt(4) -> vmcnt(0). Never drains mid-loop.
// T5: s_setprio(1) around the MFMA cluster (cross-block arbitration; r10 +17us).
// Chunk swizzle (both-sides, rule 21): LDS slot(row,q') = row*4 + q' holds global k-chunk
// q = q' ^ ((row>>1)&3); fragment reads same XOR -> 2-way bank (free, m136).
// EPI: 0 plain (ACT gelu, ACC fp32-acc, OBF bf16 store), 3 qp, 4 embed,
//      6 fused xp(y<4: store+max over Wt)+diag(y>=4: over Wt2)
template <int EPI, int ACT, int ACC, int OBF, int KM>
__global__ __launch_bounds__(256) void mfma_gemm(
    const u16* __restrict__ A, const u16* __restrict__ Wt,
    const u16* __restrict__ Wt2,
    const float* __restrict__ bias, const float* __restrict__ posP,
    const u16* __restrict__ diagIn,
    float* __restrict__ outF, u16* __restrict__ outB,
    u16* __restrict__ diagOut, unsigned int* __restrict__ kmaxOut,
    int N, int K) {
  __shared__ __align__(16) u16 Als[12288];  // 3 bufs x 512 slots x 8 u16 (24KB)
  __shared__ __align__(16) u16 Bls[12288];
  const int K2 = K * KM;
  int tid = threadIdx.x;
  // ---- T1 bijective XCD swizzle, y-fastest work order ----
  int tot = gridDim.x * gridDim.y;
  int f = blockIdx.x + gridDim.x * blockIdx.y;
  int wid = (f & 7) * (tot >> 3) + (f >> 3);
  int ny = gridDim.y;                       // power of 2 (2,4,8)
  int lg = 31 - __clz(ny);
  int xb = wid >> lg;
  int yb = wid & (ny - 1);
  int bm = xb * 128;
  const u16* Wp = Wt;
  int bn = yb * 128;
  if (EPI == 6 && yb >= 4) { Wp = Wt2; bn = (yb - 4) * 128; }
  int w = tid >> 6, lane = tid & 63;
  int wm = w >> 1, wn = w & 1;
  int lr = lane & 15, lq = lane >> 4;
  f32x4 acc[4][4];
#pragma unroll
  for (int i = 0; i < 4; ++i)
#pragma unroll
    for (int j = 0; j < 4; ++j) acc[i][j] = (f32x4){0.f, 0.f, 0.f, 0.f};
  // staging lane geometry (see header comment)
  int sub = lane >> 2;                         // row within 16-row group
  int qsw = (lane & 3) ^ ((lane >> 3) & 3);    // global k-chunk this lane fetches
  const u16* gA0 = A + (size_t)(bm + 32 * w + sub) * K + qsw * 8;
  const u16* gA1 = gA0 + (size_t)16 * K;
  const u16* gB0 = Wp + (size_t)(bn + 32 * w + sub) * K2 + qsw * 8;
  const u16* gB1 = gB0 + (size_t)16 * K2;
  u16* lA0 = Als + (w * 2 + 0) * 512;          // wave-uniform LDS bases (slot*8 u16)
  u16* lA1 = Als + (w * 2 + 1) * 512;
  u16* lB0 = Bls + (w * 2 + 0) * 512;
  u16* lB1 = Bls + (w * 2 + 1) * 512;
  // fragment read base (chunk swizzle folded in; per-lane constant)
  int qswr = lq ^ ((lr >> 1) & 3);
  int aB = wm * 256 + lr * 4 + qswr;
  int bB = wn * 256 + lr * 4 + qswr;

#define STAGE(buf, kk) do { \
    int ka_ = (kk) & (K - 1); int kb_ = (kk); int lo_ = (buf) * 4096; \
    gload16(gA0 + ka_, lA0 + lo_); \
    gload16(gA1 + ka_, lA1 + lo_); \
    gload16(gB0 + kb_, lB0 + lo_); \
    gload16(gB1 + kb_, lB1 + lo_); \
  } while (0)

  const int nt = K2 / 32;                      // >= 4 for all instantiations
  STAGE(0, 0);
  STAGE(1, 32);
  STAGE(2, 64);
  int cur = 0;
  for (int t = 0; t < nt; ++t) {
    if (t + 2 < nt)      asm volatile("s_waitcnt vmcnt(8)" ::: "memory");
    else if (t + 1 < nt) asm volatile("s_waitcnt vmcnt(4)" ::: "memory");
    else                 asm volatile("s_waitcnt vmcnt(0)" ::: "memory");
    __builtin_amdgcn_s_barrier();              // all waves' cur-buf loads landed
    __builtin_amdgcn_sched_barrier(0);         // pin: no ds_read above barrier1
    const bf16x8* Ab = (const bf16x8*)(Als + cur * 4096);
    const bf16x8* Bb = (const bf16x8*)(Bls + cur * 4096);
    bf16x8 af[4], bfr[4];
#pragma unroll
    for (int mi = 0; mi < 4; ++mi) af[mi] = Ab[aB + mi * 64];
#pragma unroll
    for (int ni = 0; ni < 4; ++ni) bfr[ni] = Bb[bB + ni * 64];
    __builtin_amdgcn_s_setprio(1);             // T5: favor MFMA-entering waves
#pragma unroll
    for (int mi = 0; mi < 4; ++mi)
#pragma unroll
      for (int ni = 0; ni < 4; ++ni)
        acc[mi][ni] = __builtin_amdgcn_mfma_f32_16x16x32_bf16(af[mi], bfr[ni], acc[mi][ni], 0, 0, 0);
    __builtin_amdgcn_s_setprio(0);
    asm volatile("s_waitcnt lgkmcnt(0)" ::: "memory");  // my ds_reads complete
    __builtin_amdgcn_sched_barrier(0);
    __builtin_amdgcn_s_barrier();              // all waves done reading cur buf
    __builtin_amdgcn_sched_barrier(0);         // pin: STAGE stays below barrier2
    if (t + 3 < nt) STAGE(cur, (t + 3) * 32);
    cur = (cur == 2) ? 0 : cur + 1;
  }
#undef STAGE
  // ---- epilogues ----  C/D: col = lane&15, row = (lane>>4)*4 + r  [m89-verified]
  if (EPI == 0) {
#pragma unroll
    for (int ni = 0; ni < 4; ++ni) {
      int col = bn + wn * 64 + ni * 16 + lr;
      float bv = bias ? bias[col] : 0.f;
#pragma unroll
      for (int mi = 0; mi < 4; ++mi)
#pragma unroll
        for (int rr = 0; rr < 4; ++rr) {
          int rowg = bm + wm * 64 + mi * 16 + lq * 4 + rr;
          float val = acc[mi][ni][rr] + bv;
          if (ACT) val = geluf(val);
          size_t o = (size_t)rowg * N + col;
          if (OBF) outB[o] = f2bf(val);
          else if (ACC) outF[o] += val;
          else outF[o] = val;
        }
    }
  }
  if (EPI == 3) {  // qp: in-wave row-max over the head's 64 cols, then exp; dg q-heads at +8
    int head = (bn + wn * 64) >> 6;
#pragma unroll
    for (int mi = 0; mi < 4; ++mi) {
      float rm[4] = {-3.4e38f, -3.4e38f, -3.4e38f, -3.4e38f};
#pragma unroll
      for (int ni = 0; ni < 4; ++ni)
#pragma unroll
        for (int rr = 0; rr < 4; ++rr) rm[rr] = fmaxf(rm[rr], acc[mi][ni][rr]);
#pragma unroll
      for (int rr = 0; rr < 4; ++rr) {
        float t = rm[rr];
        t = fmaxf(t, __shfl_xor(t, 1)); t = fmaxf(t, __shfl_xor(t, 2));
        t = fmaxf(t, __shfl_xor(t, 4)); t = fmaxf(t, __shfl_xor(t, 8));
        rm[rr] = t;
      }
#pragma unroll
      for (int rr = 0; rr < 4; ++rr) {
        int rowg = bm + wm * 64 + mi * 16 + lq * 4 + rr;
        float dgv = bf2f(diagIn[(size_t)rowg * 16 + 8 + head]);
#pragma unroll
        for (int ni = 0; ni < 4; ++ni) {
          int col = bn + wn * 64 + ni * 16 + lr;
          float v = RATIO * (__expf(acc[mi][ni][rr] - dgv - rm[rr]) + KEPS);
          outB[(size_t)rowg * N + col] = f2bf(v);
        }
      }
    }
  }
  if (EPI == 4) {  // embed: + bias + pos, fp32 store (N==256)
#pragma unroll
    for (int ni = 0; ni < 4; ++ni) {
      int col = bn + wn * 64 + ni * 16 + lr;
      float bv = bias[col];
#pragma unroll
      for (int mi = 0; mi < 4; ++mi)
#pragma unroll
        for (int rr = 0; rr < 4; ++rr) {
          int rowg = bm + wm * 64 + mi * 16 + lq * 4 + rr;
          outF[(size_t)rowg * 256 + col] =
              acc[mi][ni][rr] + bv + posP[(size_t)(rowg & (D_S - 1)) * 256 + col];
        }
    }
  }
  if (EPI == 6) {
    if (yb < 4) {  // xp: store bf16 + global max per (b, head)
      float mx = -3.4e38f;
#pragma unroll
      for (int mi = 0; mi < 4; ++mi)
#pragma unroll
        for (int ni = 0; ni < 4; ++ni)
#pragma unroll
          for (int rr = 0; rr < 4; ++rr) {
            float v = acc[mi][ni][rr];
            mx = fmaxf(mx, v);
            int rowg = bm + wm * 64 + mi * 16 + lq * 4 + rr;
            int col = bn + wn * 64 + ni * 16 + lr;
            outB[(size_t)rowg * N + col] = f2bf(v);
          }
#pragma unroll
      for (int off = 1; off < 64; off <<= 1) mx = fmaxf(mx, __shfl_xor(mx, off));
      if (lane == 0) {
        int b = bm >> 13;
        int head = (bn + wn * 64) >> 6;
        unsigned int u = __float_as_uint(mx);
        unsigned int key = (u & 0x80000000u) ? ~u : (u | 0x80000000u);
        atomicMax(kmaxOut + b * 8 + head, key);
      }
    } else {  // diag per head (32 cols); wave spans 2 heads; dg layout [t][16]
      const float c05n2 = 0.5f * NORMALIZER * NORMALIZER;
      int hb = (bn + wn * 64) >> 5;
#pragma unroll
      for (int mi = 0; mi < 4; ++mi) {
        float s0[4] = {0.f, 0.f, 0.f, 0.f}, s1[4] = {0.f, 0.f, 0.f, 0.f};
#pragma unroll
        for (int ni = 0; ni < 4; ++ni)
#pragma unroll
          for (int rr = 0; rr < 4; ++rr) {
            float v = acc[mi][ni][rr];
            if (ni < 2) s0[rr] += v * v; else s1[rr] += v * v;
          }
#pragma unroll
        for (int rr = 0; rr < 4; ++rr) {
          float a = s0[rr], b = s1[rr];
          a += __shfl_xor(a, 1); a += __shfl_xor(a, 2); a += __shfl_xor(a, 4); a += __shfl_xor(a, 8);
          b += __shfl_xor(b, 1); b += __shfl_xor(b, 2); b += __shfl_xor(b, 4); b += __shfl_xor(b, 8);
          if (lr == 0) {
            int rowg = bm + wm * 64 + mi * 16 + lq * 4 + rr;
            diagOut[(size_t)rowg * 16 + hb] = f2bf(c05n2 * a);
            diagOut[(size_t)rowg * 16 + hb + 1] = f2bf(c05n2 * b);
          }
        }
      }
    }
  }
}

// ===== ctxaccum: kp computed inline from raw xp (exp fused); part[m][e] = sum kp*v =====
__global__ __launch_bounds__(256) void ctxaccum_kernel(
    const u16* __restrict__ xp, const u16* __restrict__ v,
    const u16* __restrict__ dg, const unsigned int* __restrict__ kmaxk,
    float* __restrict__ part, float* __restrict__ partk, int hf) {
  __shared__ float kpS[64 * 64];
  __shared__ float vS[64 * 32];
  int tid = threadIdx.x;
  int bl = blockIdx.x >> 3, head = blockIdx.x & 7, c = blockIdx.y;
  int n0l = bl * 8192 + c * 512;   // within half (32768 tokens)
  int bhg = (hf * 4 + bl) * 8 + head;
  int tg0 = hf * 32768 + n0l;
  float mx = dec_max(kmaxk[bhg]);
  int m = tid & 63, eg = tid >> 6;
  float acc[8] = {};
  float ks = 0.f;
  const u16* kpb = xp + (size_t)tg0 * 512 + head * 64;
  const u16* vb = v + (size_t)n0l * 256 + head * 32;
  for (int tile = 0; tile < 8; ++tile) {
    int nb = tile * 64;
    __syncthreads();
#pragma unroll
    for (int i = 0; i < 2; ++i) {
      int idx8 = tid + i * 256;          // 512 chunks of 8
      int row = idx8 >> 3, c8 = (idx8 & 7) * 8;
      float dgrow = bf2f(dg[(size_t)(tg0 + nb + row) * 16 + head]);
      u16 tmp[8];
      *(uint4*)tmp = *(const uint4*)(kpb + (size_t)(nb + row) * 512 + c8);
#pragma unroll
      for (int j = 0; j < 8; ++j)
        kpS[row * 64 + c8 + j] = RATIO * (__expf(bf2f(tmp[j]) - dgrow - mx) + KEPS);
    }
    {
      int row = tid >> 2, c8 = (tid & 3) * 8;
      u16 tmp[8];
      *(uint4*)tmp = *(const uint4*)(vb + (size_t)(nb + row) * 256 + c8);
#pragma unroll
      for (int j = 0; j < 8; ++j) vS[row * 32 + c8 + j] = bf2f(tmp[j]);
    }
    __syncthreads();
#pragma unroll 4
    for (int n = 0; n < 64; ++n) {
      float kv = kpS[n * 64 + m];
      if (eg == 0) ks += kv;
      const float* vr = &vS[n * 32 + eg * 8];
#pragma unroll
      for (int j = 0; j < 8; ++j) acc[j] += kv * vr[j];
    }
  }
  float* pp = part + ((size_t)bhg * 16 + c) * 2048 + m * 32 + eg * 8;
#pragma unroll
  for (int j = 0; j < 8; ++j) pp[j] = acc[j];
  if (eg == 0) partk[((size_t)bhg * 16 + c) * 64 + m] = ks;
}

__global__ __launch_bounds__(256) void ctxreduce_kernel(
    const float* __restrict__ part, const float* __restrict__ partk,
    float* __restrict__ ctx, float* __restrict__ ksum) {
  int bh = blockIdx.x, tid = threadIdx.x;
#pragma unroll
  for (int i = 0; i < 8; ++i) {
    int idx = tid + i * 256;
    float s = 0.f;
#pragma unroll
    for (int cc = 0; cc < 16; ++cc)
      s += part[((size_t)bh * 16 + cc) * 2048 + idx];
    ctx[(size_t)bh * 2048 + idx] = s;
  }
  if (tid < 64) {
    float s = 0.f;
#pragma unroll
    for (int cc = 0; cc < 16; ++cc) s += partk[((size_t)bh * 16 + cc) * 64 + tid];
    ksum[bh * 64 + tid] = s;
  }
}

// ===== btprep: pack [ctx | ksum | 0] into B-operand hi/lo bf16: Bt[bh][48][BTS] =====
__global__ __launch_bounds__(256) void btprep_kernel(
    const float* __restrict__ ctx, const float* __restrict__ ksum,
    u16* __restrict__ Bt) {
  int bh = blockIdx.x, tid = threadIdx.x;
  for (int idx = tid; idx < 48 * 64; idx += 256) {
    int n = idx >> 6, k = idx & 63;
    float v = 0.f;
    if (n < 32) v = ctx[(size_t)bh * 2048 + k * 32 + n];
    else if (n == 32) v = ksum[bh * 64 + k];
    u16 hi = f2bf(v);
    u16 lo = f2bf(v - bf2f(hi));
    u16* row = Bt + ((size_t)bh * 48 + n) * BTS;
    row[k] = hi;
    row[64 + k] = lo;
  }
}

// ===== attnout via MFMA: ao = (qp@ctx)/(qp@ksum) =====
__global__ __launch_bounds__(256) void attnout_kernel(
    const u16* __restrict__ qp, const u16* __restrict__ Bt,
    u16* __restrict__ ao, int hf) {
  __shared__ __align__(16) u16 BtS[48 * BTS];
  int tid = threadIdx.x;
  int rb = blockIdx.x, head = blockIdx.y;
  int t0l = rb * 128;
  int bhg = ((hf * 32768 + t0l) >> 13) * 8 + head;
  {
    const uint4* src = (const uint4*)(Bt + (size_t)bhg * 48 * BTS);
    for (int i = tid; i < 48 * BTS / 8; i += 256) ((uint4*)BtS)[i] = src[i];
  }
  __syncthreads();
  int w = tid >> 6, lane = tid & 63;
  int lr = lane & 15, lq = lane >> 4;
  int tw = t0l + w * 32;
  const u16* qpb = qp + (size_t)(hf * 32768 + tw) * 512 + head * 64;
  bf16x8 af[2][2];
#pragma unroll
  for (int mt = 0; mt < 2; ++mt)
#pragma unroll
    for (int kc = 0; kc < 2; ++kc)
      af[mt][kc] = *(const bf16x8*)(qpb + (size_t)(mt * 16 + lr) * 512 + kc * 32 + lq * 8);
  f32x4 c0[2], c1[2], c2[2];
#pragma unroll
  for (int mt = 0; mt < 2; ++mt) {
    c0[mt] = (f32x4){0.f, 0.f, 0.f, 0.f};
    c1[mt] = (f32x4){0.f, 0.f, 0.f, 0.f};
    c2[mt] = (f32x4){0.f, 0.f, 0.f, 0.f};
  }
  __builtin_amdgcn_s_setprio(1);               // T5 (attn-positive, m191)
#pragma unroll
  for (int kc = 0; kc < 4; ++kc) {
    bf16x8 b0 = *(const bf16x8*)(BtS + (size_t)(0 * 16 + lr) * BTS + kc * 32 + lq * 8);
    bf16x8 b1 = *(const bf16x8*)(BtS + (size_t)(1 * 16 + lr) * BTS + kc * 32 + lq * 8);
    bf16x8 b2 = *(const bf16x8*)(BtS + (size_t)(2 * 16 + lr) * BTS + kc * 32 + lq * 8);
#pragma unroll
    for (int mt = 0; mt < 2; ++mt) {
      bf16x8 a = af[mt][kc & 1];
      c0[mt] = __builtin_amdgcn_mfma_f32_16x16x32_bf16(a, b0, c0[mt], 0, 0, 0);
      c1[mt] = __builtin_amdgcn_mfma_f32_16x16x32_bf16(a, b1, c1[mt], 0, 0, 0);
      c2[mt] = __builtin_amdgcn_mfma_f32_16x16x32_bf16(a, b2, c2[mt], 0, 0, 0);
    }
  }
  __builtin_amdgcn_s_setprio(0);
#pragma unroll
  for (int mt = 0; mt < 2; ++mt)
#pragma unroll
    for (int rr = 0; rr < 4; ++rr) {
      float den = __shfl(c2[mt][rr], lane & 48);
      int rowl = tw + mt * 16 + lq * 4 + rr;
      float inv = 1.f / den;
      ao[(size_t)rowl * 256 + head * 32 + lr] = f2bf(c0[mt][rr] * inv);
      ao[(size_t)rowl * 256 + head * 32 + 16 + lr] = f2bf(c1[mt][rr] * inv);
    }
}

// ================= mean pool + final FC (fp32 h) =================
__global__ __launch_bounds__(256) void pool_kernel(
    const float* __restrict__ h, float* __restrict__ pooled) {
  int b = blockIdx.x, chunk = blockIdx.y, j = threadIdx.x;
  const float* hp = h + (size_t)(b * D_S + chunk * 256) * 256 + j;
  float acc = 0.f;
#pragma unroll 4
  for (int s = 0; s < 256; ++s) acc += hp[(size_t)s * 256];
  atomicAdd(pooled + b * 256 + j, acc);
}

__global__ __launch_bounds__(64) void final_kernel(
    const float* __restrict__ pooled, const float* __restrict__ fcw,
    const float* __restrict__ fcb, float* __restrict__ out) {
  int tid = threadIdx.x;
  if (tid >= 16) return;
  int b = tid >> 1, c = tid & 1;
  float acc = 0.f;
  for (int j = 0; j < 256; ++j) acc += pooled[b * 256 + j] * fcw[j * 2 + c];
  out[b * 2 + c] = acc * (1.f / 8192.f) + fcb[c];
}

extern "C" void kernel_launch(void* const* d_in, const int* in_sizes, int n_in,
                              void* d_out, int out_size, void* d_ws, size_t ws_size,
                              hipStream_t stream) {
  const float* x     = (const float*)d_in[0];
  const float* emb_w = (const float*)d_in[1];
  const float* emb_b = (const float*)d_in[2];
  const float* pos   = (const float*)d_in[3];
  const float* ln1_g = (const float*)d_in[4];
  const float* ln1_b = (const float*)d_in[5];
  const float* wq    = (const float*)d_in[6];
  const float* wk    = (const float*)d_in[7];
  const float* wv    = (const float*)d_in[8];
  const float* wo    = (const float*)d_in[9];
  const float* bo    = (const float*)d_in[10];
  const float* ln2_g = (const float*)d_in[11];
  const float* ln2_b = (const float*)d_in[12];
  const float* w1    = (const float*)d_in[13];
  const float* b1    = (const float*)d_in[14];
  const float* w2    = (const float*)d_in[15];
  const float* b2    = (const float*)d_in[16];
  const float* proj  = (const float*)d_in[17];
  const float* fc_w  = (const float*)d_in[18];
  const float* fc_b  = (const float*)d_in[19];

  if (ws_size < NEED_BYTES) {
    report_kernel<<<1, 64, 0, stream>>>((float*)d_out, (float)ws_size);
    return;
  }

  float* ws = (float*)d_ws;
  float* h      = ws + OFF_H;
  u16* xnb      = (u16*)(ws + OFF_XNB);
  u16* BIG      = (u16*)(ws + OFF_BIG);
  u16* Vb       = (u16*)(ws + OFF_V);
  u16* WKPt     = (u16*)(ws + OFF_WKP);
  u16* WQPt     = (u16*)(ws + OFF_WQP);
  u16* WKt      = (u16*)(ws + OFF_WK);
  u16* WQt      = (u16*)(ws + OFF_WQ);
  u16* WVt      = (u16*)(ws + OFF_WV);
  u16* WOt      = (u16*)(ws + OFF_WO);
  u16* W1t      = (u16*)(ws + OFF_W1);
  u16* W2t      = (u16*)(ws + OFF_W2);
  u16* dg       = (u16*)(ws + OFF_DG);
  unsigned int* kmaxk = (unsigned int*)(ws + OFF_KMAX);
  float* part   = ws + OFF_PART;
  u16* Bt       = (u16*)(ws + OFF_PART);  // reuses part after ctxreduce (btprep reads ctx/ksum only)
  float* partk  = ws + OFF_PARTK;
  float* ctx    = ws + OFF_CTX;
  float* ksum   = ws + OFF_KSUM;
  float* pooled = ws + OFF_POOL;

  // ---- embed as MFMA GEMM ----
  xcvt_kernel<<<4096, 256, 0, stream>>>(x, BIG);
  wsplit_kernel<<<64, 256, 0, stream>>>(emb_w, WKPt, 64, 256, 8);
  mfma_gemm<4, 0, 0, 0, 2><<<dim3(512, 2), 256, 0, stream>>>(
      BIG, WKPt, nullptr, emb_b, pos, nullptr, h, nullptr, nullptr, nullptr, 256, 64);

  for (int l = 0; l < D_L; ++l) {
    const float* pj = proj + l * 2048;
    ln_kernel<<<TOK / 4, 256, 0, stream>>>(h, xnb, ln1_g + l * 256, ln1_b + l * 256);
    wprep_kernel<<<4096, 256, 0, stream>>>(
        wk + l * 65536, wq + l * 65536, wv + l * 65536, wo + l * 65536,
        w1 + l * 262144, w2 + l * 262144, pj,
        WKPt, WQPt, WKt, WQt, WVt, WOt, W1t, W2t, kmaxk);

    // fused xp(+kmax) and diag(k|q): one launch, y<4 xp / y>=4 diag
    mfma_gemm<6, 0, 0, 1, 1><<<dim3(512, 8), 256, 0, stream>>>(
        xnb, WKPt, WKt, nullptr, nullptr, nullptr, nullptr, BIG, dg, kmaxk, 512, 256);
    // context accumulation per half (exp fused into staging)
    for (int hf = 0; hf < 2; ++hf) {
      const u16* xh = xnb + (size_t)hf * 32768 * 256;
      mfma_gemm<0, 0, 0, 1, 1><<<dim3(256, 2), 256, 0, stream>>>(
          xh, WVt, nullptr, nullptr, nullptr, nullptr, nullptr, Vb, nullptr, nullptr, 256, 256);
      ctxaccum_kernel<<<dim3(32, 16), 256, 0, stream>>>(BIG, Vb, dg, kmaxk, part, partk, hf);
    }
    ctxreduce_kernel<<<64, 256, 0, stream>>>(part, partk, ctx, ksum);
    btprep_kernel<<<64, 256, 0, stream>>>(ctx, ksum, Bt);
    // qp (overwrites BIG; xp dead), single-plane WQP
    mfma_gemm<3, 0, 0, 1, 1><<<dim3(512, 4), 256, 0, stream>>>(
        xnb, WQPt, nullptr, nullptr, nullptr, dg, nullptr, BIG, nullptr, nullptr, 512, 256);
    for (int hf = 0; hf < 2; ++hf) {
      float* hh = h + (size_t)hf * 32768 * 256;
      attnout_kernel<<<dim3(256, 8), 256, 0, stream>>>(BIG, Bt, Vb, hf);
      mfma_gemm<0, 0, 1, 0, 1><<<dim3(256, 2), 256, 0, stream>>>(
          Vb, WOt, nullptr, bo + l * 256, nullptr, nullptr, hh, nullptr, nullptr, nullptr, 256, 256);
    }

    ln_kernel<<<TOK / 4, 256, 0, stream>>>(h, xnb, ln2_g + l * 256, ln2_b + l * 256);
    for (int hf = 0; hf < 2; ++hf) {
      const u16* xh = xnb + (size_t)hf * 32768 * 256;
      float* hh = h + (size_t)hf * 32768 * 256;
      // FFN single-plane bf16 (KM=1)
      mfma_gemm<0, 1, 0, 1, 1><<<dim3(256, 8), 256, 0, stream>>>(
          xh, W1t, nullptr, b1 + l * 1024, nullptr, nullptr, nullptr, BIG, nullptr, nullptr, 1024, 256);
      mfma_gemm<0, 0, 1, 0, 1><<<dim3(256, 2), 256, 0, stream>>>(
          BIG, W2t, nullptr, b2 + l * 256, nullptr, nullptr, hh, nullptr, nullptr, nullptr, 256, 1024);
    }
  }

  zero_kernel<<<8, 256, 0, stream>>>(pooled, 2048);
  pool_kernel<<<dim3(8, 32), 256, 0, stream>>>(h, pooled);
  final_kernel<<<1, 64, 0, stream>>>(pooled, fc_w, fc_b, (float*)d_out);
}

// Round 13
// 2125.643 us; speedup vs baseline: 1.0191x; 1.0162x over previous
//
#include <hip/hip_runtime.h>
#include <math.h>

typedef unsigned short u16;
typedef __attribute__((ext_vector_type(8))) short bf16x8;
typedef __attribute__((ext_vector_type(4))) float f32x4;

// ---- problem dims ----
static constexpr int D_S = 8192;
static constexpr int D_L = 4;
static constexpr int TOK = 65536;
static constexpr float NORMALIZER = 0.4204482076268573f;  // 32^-0.25
static constexpr float RATIO = 0.125f;                    // 64^-0.5
static constexpr float KEPS = 1e-4f;

// ---- workspace layout (float slots) ----
static constexpr size_t OFF_H     = 0;
static constexpr size_t OFF_XNB   = 16777216;
static constexpr size_t OFF_BIG   = 25165824;
static constexpr size_t OFF_V     = 41943040;
static constexpr size_t OFF_WKP   = 46137344;
static constexpr size_t OFF_WQP   = 46268416;
static constexpr size_t OFF_WK    = 46399488;
static constexpr size_t OFF_WQ    = 46465024;
static constexpr size_t OFF_WV    = 46530560;
static constexpr size_t OFF_WO    = 46596096;
static constexpr size_t OFF_W1    = 46661632;
static constexpr size_t OFF_W2    = 46923776;
static constexpr size_t OFF_DG    = 47185920;
static constexpr size_t OFF_KMAX  = 47710208;
static constexpr size_t OFF_PART  = 47710272;
static constexpr size_t OFF_PARTK = 49807424;
static constexpr size_t OFF_CTX   = 49872960;
static constexpr size_t OFF_KSUM  = 50004032;
static constexpr size_t OFF_POOL  = 50008128;
static constexpr size_t NEED_BYTES = 200040704;

static constexpr int BTS = 136;  // Bt row stride in u16 (128 + 8 pad)

static __device__ __forceinline__ float bf2f(u16 u) {
  return __uint_as_float(((unsigned int)u) << 16);
}
static __device__ __forceinline__ u16 f2bf(float f) {
  unsigned int u = __float_as_uint(f);
  u = (u + 0x7fffu + ((u >> 16) & 1u)) >> 16;
  return (u16)u;
}
static __device__ __forceinline__ float geluf(float v) {
  return 0.5f * v * (1.f + erff(v * 0.70710678118654752f));
}
static __device__ __forceinline__ float dec_max(unsigned int mk) {
  return __uint_as_float((mk & 0x80000000u) ? (mk & 0x7fffffffu) : ~mk);
}

// async global->LDS, 16B per lane; dest = wave-uniform base + lane*16 (m97 pattern)
static __device__ __forceinline__ void gload16(const u16* g, u16* l) {
  __builtin_amdgcn_global_load_lds(
      (const __attribute__((address_space(1))) unsigned int*)g,
      (__attribute__((address_space(3))) unsigned int*)l, 16, 0, 0);
}

__global__ void report_kernel(float* out, float v) {
  if (threadIdx.x < 16) out[threadIdx.x] = v;
}

__global__ __launch_bounds__(256) void zero_kernel(float* p, int n) {
  int i = blockIdx.x * 256 + threadIdx.x;
  if (i < n) p[i] = 0.f;
}

// ================= x -> bf16 =================
__global__ __launch_bounds__(256) void xcvt_kernel(const float* __restrict__ x,
                                                   u16* __restrict__ xb) {
  int i4 = (blockIdx.x * 256 + threadIdx.x) * 4;
  float4 v = *(const float4*)(x + i4);
  u16 o[4] = {f2bf(v.x), f2bf(v.y), f2bf(v.z), f2bf(v.w)};
  *(uint2*)(xb + i4) = *(uint2*)o;
}

// ================= layernorm: fp32 in, bf16 out =================
__global__ __launch_bounds__(256) void ln_kernel(
    const float* __restrict__ src, u16* __restrict__ dst,
    const float* __restrict__ g, const float* __restrict__ b) {
  int wv = threadIdx.x >> 6, lane = threadIdx.x & 63;
  int t = blockIdx.x * 4 + wv;
  const float4 v = *(const float4*)(src + (size_t)t * 256 + lane * 4);
  float s1 = v.x + v.y + v.z + v.w;
  float s2 = v.x * v.x + v.y * v.y + v.z * v.z + v.w * v.w;
  for (int off = 32; off; off >>= 1) {
    s1 += __shfl_xor(s1, off);
    s2 += __shfl_xor(s2, off);
  }
  float mu = s1 * (1.f / 256.f);
  float var = s2 * (1.f / 256.f) - mu * mu;
  float rs = rsqrtf(var + 1e-5f);
  float4 gg = *(const float4*)(g + lane * 4);
  float4 bb = *(const float4*)(b + lane * 4);
  u16 o0 = f2bf((v.x - mu) * rs * gg.x + bb.x);
  u16 o1 = f2bf((v.y - mu) * rs * gg.y + bb.y);
  u16 o2 = f2bf((v.z - mu) * rs * gg.z + bb.z);
  u16 o3 = f2bf((v.w - mu) * rs * gg.w + bb.w);
  uint2 pk;
  pk.x = (unsigned)o0 | ((unsigned)o1 << 16);
  pk.y = (unsigned)o2 | ((unsigned)o3 << 16);
  *(uint2*)(dst + (size_t)t * 256 + lane * 4) = pk;
}

// ===== embed weight split (hi/lo), used once pre-loop =====
__global__ __launch_bounds__(256) void wsplit_kernel(
    const float* __restrict__ W, u16* __restrict__ Wt, int K, int N, int nb) {
  int i = blockIdx.x * 256 + threadIdx.x;
  int k = i >> nb, n = i & (N - 1);
  float val = W[i];
  u16 hi = f2bf(val);
  u16 lo = f2bf(val - bf2f(hi));
  Wt[(size_t)n * 2 * K + k] = hi;
  Wt[(size_t)n * 2 * K + K + k] = lo;
}

// ===== merged per-layer weight prep (all single-plane except embed) =====
__global__ __launch_bounds__(256) void wprep_kernel(
    const float* __restrict__ wk, const float* __restrict__ wq,
    const float* __restrict__ wv, const float* __restrict__ wo,
    const float* __restrict__ w1, const float* __restrict__ w2,
    const float* __restrict__ proj,
    u16* __restrict__ WKP, u16* __restrict__ WQP,
    u16* __restrict__ WKt, u16* __restrict__ WQt,
    u16* __restrict__ WVt, u16* __restrict__ WOt,
    u16* __restrict__ W1t, u16* __restrict__ W2t,
    unsigned int* __restrict__ kmaxk) {
  int gi = blockIdx.x * 256 + threadIdx.x;
  if (gi < 64) kmaxk[gi] = 0u;
  if (gi < 262144) {  // WKP / WQP: proj-folded single-plane
    int i = gi & 131071;
    const float* w = (gi < 131072) ? wk : wq;
    u16* Wt = (gi < 131072) ? WKP : WQP;
    int k = i & 255, n = i >> 8;
    int head = n >> 6, m = n & 63;
    float s = 0.f;
#pragma unroll
    for (int d = 0; d < 32; ++d) s += w[k * 256 + head * 32 + d] * proj[m * 32 + d];
    Wt[(size_t)n * 256 + k] = f2bf(s * NORMALIZER);
  } else if (gi < 393216) {  // WKt / WQt single-plane
    int i = gi - 262144;
    const float* W = (i < 65536) ? wk : wq;
    u16* T = (i < 65536) ? WKt : WQt;
    int j = i & 65535;
    int k = j >> 8, n = j & 255;
    T[(size_t)n * 256 + k] = f2bf(W[j]);
  } else if (gi < 524288) {  // WVt / WOt single-plane
    int i = gi - 393216;
    const float* W = (i < 65536) ? wv : wo;
    u16* T = (i < 65536) ? WVt : WOt;
    int j = i & 65535;
    int k = j >> 8, n = j & 255;
    T[(size_t)n * 256 + k] = f2bf(W[j]);
  } else if (gi < 786432) {  // W1 single-plane: K=256, N=1024
    int i = gi - 524288;
    int k = i >> 10, n = i & 1023;
    W1t[(size_t)n * 256 + k] = f2bf(w1[i]);
  } else {                   // W2 single-plane: K=1024, N=256
    int i = gi - 786432;
    int k = i >> 8, n = i & 255;
    W2t[(size_t)n * 1024 + k] = f2bf(w2[i]);
  }
}

// ================= MFMA GEMM: 128x128 tile, A bf16 [M][K], Wt bf16 [N][K*KM] =================
// KM=2: hi/lo split weights; KM=1: single-plane.
// T1 XCD swizzle (bijective), y-fastest -> A-panel L2 reuse per XCD.
// Staging: gload_lds width=16, TRIPLE-buffered counted-vmcnt pipeline (T4, r6/r7 proven):
//   prologue stages 3 bufs (12 in flight); steady iter waits vmcnt(8), computes,
//   raw-barriers, stages t+3. Tail: vmcnt(4) -> vmcnt(0). Never drains mid-loop.
// T5: s_setprio(1) around the MFMA cluster (cross-block arbitration; r10 best).
// Chunk swizzle (both-sides, rule 21): LDS slot(row,q') = row*4 + q' holds global k-chunk
// q = q' ^ ((row>>1)&3); fragment reads same XOR -> 2-way bank (free, m136).
// EPI: 0 plain (ACT gelu, ACC fp32-acc, OBF bf16 store), 3 qp, 4 embed,
//      6 fused xp(y<4: store+max over Wt)+diag(y>=4: over Wt2)
template <int EPI, int ACT, int ACC, int OBF, int KM>
__global__ __launch_bounds__(256) void mfma_gemm(
    const u16* __restrict__ A, const u16* __restrict__ Wt,
    const u16* __restrict__ Wt2,
    const float* __restrict__ bias, const float* __restrict__ posP,
    const u16* __restrict__ diagIn,
    float* __restrict__ outF, u16* __restrict__ outB,
    u16* __restrict__ diagOut, unsigned int* __restrict__ kmaxOut,
    int N, int K) {
  __shared__ __align__(16) u16 Als[12288];  // 3 bufs x 512 slots x 8 u16 (24KB)
  __shared__ __align__(16) u16 Bls[12288];
  const int K2 = K * KM;
  int tid = threadIdx.x;
  // ---- T1 bijective XCD swizzle, y-fastest work order ----
  int tot = gridDim.x * gridDim.y;
  int f = blockIdx.x + gridDim.x * blockIdx.y;
  int wid = (f & 7) * (tot >> 3) + (f >> 3);
  int ny = gridDim.y;                       // power of 2 (2,4,8)
  int lg = 31 - __clz(ny);
  int xb = wid >> lg;
  int yb = wid & (ny - 1);
  int bm = xb * 128;
  const u16* Wp = Wt;
  int bn = yb * 128;
  if (EPI == 6 && yb >= 4) { Wp = Wt2; bn = (yb - 4) * 128; }
  int w = tid >> 6, lane = tid & 63;
  int wm = w >> 1, wn = w & 1;
  int lr = lane & 15, lq = lane >> 4;
  f32x4 acc[4][4];
#pragma unroll
  for (int i = 0; i < 4; ++i)
#pragma unroll
    for (int j = 0; j < 4; ++j) acc[i][j] = (f32x4){0.f, 0.f, 0.f, 0.f};
  // staging lane geometry (see header comment)
  int sub = lane >> 2;                         // row within 16-row group
  int qsw = (lane & 3) ^ ((lane >> 3) & 3);    // global k-chunk this lane fetches
  const u16* gA0 = A + (size_t)(bm + 32 * w + sub) * K + qsw * 8;
  const u16* gA1 = gA0 + (size_t)16 * K;
  const u16* gB0 = Wp + (size_t)(bn + 32 * w + sub) * K2 + qsw * 8;
  const u16* gB1 = gB0 + (size_t)16 * K2;
  u16* lA0 = Als + (w * 2 + 0) * 512;          // wave-uniform LDS bases (slot*8 u16)
  u16* lA1 = Als + (w * 2 + 1) * 512;
  u16* lB0 = Bls + (w * 2 + 0) * 512;
  u16* lB1 = Bls + (w * 2 + 1) * 512;
  // fragment read base (chunk swizzle folded in; per-lane constant)
  int qswr = lq ^ ((lr >> 1) & 3);
  int aB = wm * 256 + lr * 4 + qswr;
  int bB = wn * 256 + lr * 4 + qswr;

#define STAGE(buf, kk) do { \
    int ka_ = (kk) & (K - 1); int kb_ = (kk); int lo_ = (buf) * 4096; \
    gload16(gA0 + ka_, lA0 + lo_); \
    gload16(gA1 + ka_, lA1 + lo_); \
    gload16(gB0 + kb_, lB0 + lo_); \
    gload16(gB1 + kb_, lB1 + lo_); \
  } while (0)

  const int nt = K2 / 32;                      // >= 4 for all instantiations
  STAGE(0, 0);
  STAGE(1, 32);
  STAGE(2, 64);
  int cur = 0;
  for (int t = 0; t < nt; ++t) {
    if (t + 2 < nt)      asm volatile("s_waitcnt vmcnt(8)" ::: "memory");
    else if (t + 1 < nt) asm volatile("s_waitcnt vmcnt(4)" ::: "memory");
    else                 asm volatile("s_waitcnt vmcnt(0)" ::: "memory");
    __builtin_amdgcn_s_barrier();              // all waves' cur-buf loads landed
    __builtin_amdgcn_sched_barrier(0);         // pin: no ds_read above barrier1
    const bf16x8* Ab = (const bf16x8*)(Als + cur * 4096);
    const bf16x8* Bb = (const bf16x8*)(Bls + cur * 4096);
    bf16x8 af[4], bfr[4];
#pragma unroll
    for (int mi = 0; mi < 4; ++mi) af[mi] = Ab[aB + mi * 64];
#pragma unroll
    for (int ni = 0; ni < 4; ++ni) bfr[ni] = Bb[bB + ni * 64];
    __builtin_amdgcn_s_setprio(1);             // T5: favor MFMA-entering waves
#pragma unroll
    for (int mi = 0; mi < 4; ++mi)
#pragma unroll
      for (int ni = 0; ni < 4; ++ni)
        acc[mi][ni] = __builtin_amdgcn_mfma_f32_16x16x32_bf16(af[mi], bfr[ni], acc[mi][ni], 0, 0, 0);
    __builtin_amdgcn_s_setprio(0);
    asm volatile("s_waitcnt lgkmcnt(0)" ::: "memory");  // my ds_reads complete
    __builtin_amdgcn_sched_barrier(0);
    __builtin_amdgcn_s_barrier();              // all waves done reading cur buf
    __builtin_amdgcn_sched_barrier(0);         // pin: STAGE stays below barrier2
    if (t + 3 < nt) STAGE(cur, (t + 3) * 32);
    cur = (cur == 2) ? 0 : cur + 1;
  }
#undef STAGE
  // ---- epilogues ----  C/D: col = lane&15, row = (lane>>4)*4 + r  [m89-verified]
  if (EPI == 0) {
#pragma unroll
    for (int ni = 0; ni < 4; ++ni) {
      int col = bn + wn * 64 + ni * 16 + lr;
      float bv = bias ? bias[col] : 0.f;
#pragma unroll
      for (int mi = 0; mi < 4; ++mi)
#pragma unroll
        for (int rr = 0; rr < 4; ++rr) {
          int rowg = bm + wm * 64 + mi * 16 + lq * 4 + rr;
          float val = acc[mi][ni][rr] + bv;
          if (ACT) val = geluf(val);
          size_t o = (size_t)rowg * N + col;
          if (OBF) outB[o] = f2bf(val);
          else if (ACC) outF[o] += val;
          else outF[o] = val;
        }
    }
  }
  if (EPI == 3) {  // qp: in-wave row-max over the head's 64 cols, then exp; dg q-heads at +8
    int head = (bn + wn * 64) >> 6;
#pragma unroll
    for (int mi = 0; mi < 4; ++mi) {
      float rm[4] = {-3.4e38f, -3.4e38f, -3.4e38f, -3.4e38f};
#pragma unroll
      for (int ni = 0; ni < 4; ++ni)
#pragma unroll
        for (int rr = 0; rr < 4; ++rr) rm[rr] = fmaxf(rm[rr], acc[mi][ni][rr]);
#pragma unroll
      for (int rr = 0; rr < 4; ++rr) {
        float t = rm[rr];
        t = fmaxf(t, __shfl_xor(t, 1)); t = fmaxf(t, __shfl_xor(t, 2));
        t = fmaxf(t, __shfl_xor(t, 4)); t = fmaxf(t, __shfl_xor(t, 8));
        rm[rr] = t;
      }
#pragma unroll
      for (int rr = 0; rr < 4; ++rr) {
        int rowg = bm + wm * 64 + mi * 16 + lq * 4 + rr;
        float dgv = bf2f(diagIn[(size_t)rowg * 16 + 8 + head]);
#pragma unroll
        for (int ni = 0; ni < 4; ++ni) {
          int col = bn + wn * 64 + ni * 16 + lr;
          float v = RATIO * (__expf(acc[mi][ni][rr] - dgv - rm[rr]) + KEPS);
          outB[(size_t)rowg * N + col] = f2bf(v);
        }
      }
    }
  }
  if (EPI == 4) {  // embed: + bias + pos, fp32 store (N==256)
#pragma unroll
    for (int ni = 0; ni < 4; ++ni) {
      int col = bn + wn * 64 + ni * 16 + lr;
      float bv = bias[col];
#pragma unroll
      for (int mi = 0; mi < 4; ++mi)
#pragma unroll
        for (int rr = 0; rr < 4; ++rr) {
          int rowg = bm + wm * 64 + mi * 16 + lq * 4 + rr;
          outF[(size_t)rowg * 256 + col] =
              acc[mi][ni][rr] + bv + posP[(size_t)(rowg & (D_S - 1)) * 256 + col];
        }
    }
  }
  if (EPI == 6) {
    if (yb < 4) {  // xp: store bf16 + global max per (b, head)
      float mx = -3.4e38f;
#pragma unroll
      for (int mi = 0; mi < 4; ++mi)
#pragma unroll
        for (int ni = 0; ni < 4; ++ni)
#pragma unroll
          for (int rr = 0; rr < 4; ++rr) {
            float v = acc[mi][ni][rr];
            mx = fmaxf(mx, v);
            int rowg = bm + wm * 64 + mi * 16 + lq * 4 + rr;
            int col = bn + wn * 64 + ni * 16 + lr;
            outB[(size_t)rowg * N + col] = f2bf(v);
          }
#pragma unroll
      for (int off = 1; off < 64; off <<= 1) mx = fmaxf(mx, __shfl_xor(mx, off));
      if (lane == 0) {
        int b = bm >> 13;
        int head = (bn + wn * 64) >> 6;
        unsigned int u = __float_as_uint(mx);
        unsigned int key = (u & 0x80000000u) ? ~u : (u | 0x80000000u);
        atomicMax(kmaxOut + b * 8 + head, key);
      }
    } else {  // diag per head (32 cols); wave spans 2 heads; dg layout [t][16]
      const float c05n2 = 0.5f * NORMALIZER * NORMALIZER;
      int hb = (bn + wn * 64) >> 5;
#pragma unroll
      for (int mi = 0; mi < 4; ++mi) {
        float s0[4] = {0.f, 0.f, 0.f, 0.f}, s1[4] = {0.f, 0.f, 0.f, 0.f};
#pragma unroll
        for (int ni = 0; ni < 4; ++ni)
#pragma unroll
          for (int rr = 0; rr < 4; ++rr) {
            float v = acc[mi][ni][rr];
            if (ni < 2) s0[rr] += v * v; else s1[rr] += v * v;
          }
#pragma unroll
        for (int rr = 0; rr < 4; ++rr) {
          float a = s0[rr], b = s1[rr];
          a += __shfl_xor(a, 1); a += __shfl_xor(a, 2); a += __shfl_xor(a, 4); a += __shfl_xor(a, 8);
          b += __shfl_xor(b, 1); b += __shfl_xor(b, 2); b += __shfl_xor(b, 4); b += __shfl_xor(b, 8);
          if (lr == 0) {
            int rowg = bm + wm * 64 + mi * 16 + lq * 4 + rr;
            diagOut[(size_t)rowg * 16 + hb] = f2bf(c05n2 * a);
            diagOut[(size_t)rowg * 16 + hb + 1] = f2bf(c05n2 * b);
          }
        }
      }
    }
  }
}

// ===== ctxaccum: kp computed inline from raw xp (exp fused); part[m][e] = sum kp*v =====
__global__ __launch_bounds__(256) void ctxaccum_kernel(
    const u16* __restrict__ xp, const u16* __restrict__ v,
    const u16* __restrict__ dg, const unsigned int* __restrict__ kmaxk,
    float* __restrict__ part, float* __restrict__ partk, int hf) {
  __shared__ float kpS[64 * 64];
  __shared__ float vS[64 * 32];
  int tid = threadIdx.x;
  int bl = blockIdx.x >> 3, head = blockIdx.x & 7, c = blockIdx.y;
  int n0l = bl * 8192 + c * 512;   // within half (32768 tokens)
  int bhg = (hf * 4 + bl) * 8 + head;
  int tg0 = hf * 32768 + n0l;
  float mx = dec_max(kmaxk[bhg]);
  int m = tid & 63, eg = tid >> 6;
  float acc[8] = {};
  float ks = 0.f;
  const u16* kpb = xp + (size_t)tg0 * 512 + head * 64;
  const u16* vb = v + (size_t)n0l * 256 + head * 32;
  for (int tile = 0; tile < 8; ++tile) {
    int nb = tile * 64;
    __syncthreads();
#pragma unroll
    for (int i = 0; i < 2; ++i) {
      int idx8 = tid + i * 256;          // 512 chunks of 8
      int row = idx8 >> 3, c8 = (idx8 & 7) * 8;
      float dgrow = bf2f(dg[(size_t)(tg0 + nb + row) * 16 + head]);
      u16 tmp[8];
      *(uint4*)tmp = *(const uint4*)(kpb + (size_t)(nb + row) * 512 + c8);
#pragma unroll
      for (int j = 0; j < 8; ++j)
        kpS[row * 64 + c8 + j] = RATIO * (__expf(bf2f(tmp[j]) - dgrow - mx) + KEPS);
    }
    {
      int row = tid >> 2, c8 = (tid & 3) * 8;
      u16 tmp[8];
      *(uint4*)tmp = *(const uint4*)(vb + (size_t)(nb + row) * 256 + c8);
#pragma unroll
      for (int j = 0; j < 8; ++j) vS[row * 32 + c8 + j] = bf2f(tmp[j]);
    }
    __syncthreads();
#pragma unroll 4
    for (int n = 0; n < 64; ++n) {
      float kv = kpS[n * 64 + m];
      if (eg == 0) ks += kv;
      const float* vr = &vS[n * 32 + eg * 8];
#pragma unroll
      for (int j = 0; j < 8; ++j) acc[j] += kv * vr[j];
    }
  }
  float* pp = part + ((size_t)bhg * 16 + c) * 2048 + m * 32 + eg * 8;
#pragma unroll
  for (int j = 0; j < 8; ++j) pp[j] = acc[j];
  if (eg == 0) partk[((size_t)bhg * 16 + c) * 64 + m] = ks;
}

__global__ __launch_bounds__(256) void ctxreduce_kernel(
    const float* __restrict__ part, const float* __restrict__ partk,
    float* __restrict__ ctx, float* __restrict__ ksum) {
  int bh = blockIdx.x, tid = threadIdx.x;
#pragma unroll
  for (int i = 0; i < 8; ++i) {
    int idx = tid + i * 256;
    float s = 0.f;
#pragma unroll
    for (int cc = 0; cc < 16; ++cc)
      s += part[((size_t)bh * 16 + cc) * 2048 + idx];
    ctx[(size_t)bh * 2048 + idx] = s;
  }
  if (tid < 64) {
    float s = 0.f;
#pragma unroll
    for (int cc = 0; cc < 16; ++cc) s += partk[((size_t)bh * 16 + cc) * 64 + tid];
    ksum[bh * 64 + tid] = s;
  }
}

// ===== btprep: pack [ctx | ksum | 0] into B-operand hi/lo bf16: Bt[bh][48][BTS] =====
__global__ __launch_bounds__(256) void btprep_kernel(
    const float* __restrict__ ctx, const float* __restrict__ ksum,
    u16* __restrict__ Bt) {
  int bh = blockIdx.x, tid = threadIdx.x;
  for (int idx = tid; idx < 48 * 64; idx += 256) {
    int n = idx >> 6, k = idx & 63;
    float v = 0.f;
    if (n < 32) v = ctx[(size_t)bh * 2048 + k * 32 + n];
    else if (n == 32) v = ksum[bh * 64 + k];
    u16 hi = f2bf(v);
    u16 lo = f2bf(v - bf2f(hi));
    u16* row = Bt + ((size_t)bh * 48 + n) * BTS;
    row[k] = hi;
    row[64 + k] = lo;
  }
}

// ===== attnout via MFMA: ao = (qp@ctx)/(qp@ksum) =====
__global__ __launch_bounds__(256) void attnout_kernel(
    const u16* __restrict__ qp, const u16* __restrict__ Bt,
    u16* __restrict__ ao, int hf) {
  __shared__ __align__(16) u16 BtS[48 * BTS];
  int tid = threadIdx.x;
  int rb = blockIdx.x, head = blockIdx.y;
  int t0l = rb * 128;
  int bhg = ((hf * 32768 + t0l) >> 13) * 8 + head;
  {
    const uint4* src = (const uint4*)(Bt + (size_t)bhg * 48 * BTS);
    for (int i = tid; i < 48 * BTS / 8; i += 256) ((uint4*)BtS)[i] = src[i];
  }
  __syncthreads();
  int w = tid >> 6, lane = tid & 63;
  int lr = lane & 15, lq = lane >> 4;
  int tw = t0l + w * 32;
  const u16* qpb = qp + (size_t)(hf * 32768 + tw) * 512 + head * 64;
  bf16x8 af[2][2];
#pragma unroll
  for (int mt = 0; mt < 2; ++mt)
#pragma unroll
    for (int kc = 0; kc < 2; ++kc)
      af[mt][kc] = *(const bf16x8*)(qpb + (size_t)(mt * 16 + lr) * 512 + kc * 32 + lq * 8);
  f32x4 c0[2], c1[2], c2[2];
#pragma unroll
  for (int mt = 0; mt < 2; ++mt) {
    c0[mt] = (f32x4){0.f, 0.f, 0.f, 0.f};
    c1[mt] = (f32x4){0.f, 0.f, 0.f, 0.f};
    c2[mt] = (f32x4){0.f, 0.f, 0.f, 0.f};
  }
#pragma unroll
  for (int kc = 0; kc < 4; ++kc) {
    bf16x8 b0 = *(const bf16x8*)(BtS + (size_t)(0 * 16 + lr) * BTS + kc * 32 + lq * 8);
    bf16x8 b1 = *(const bf16x8*)(BtS + (size_t)(1 * 16 + lr) * BTS + kc * 32 + lq * 8);
    bf16x8 b2 = *(const bf16x8*)(BtS + (size_t)(2 * 16 + lr) * BTS + kc * 32 + lq * 8);
#pragma unroll
    for (int mt = 0; mt < 2; ++mt) {
      bf16x8 a = af[mt][kc & 1];
      c0[mt] = __builtin_amdgcn_mfma_f32_16x16x32_bf16(a, b0, c0[mt], 0, 0, 0);
      c1[mt] = __builtin_amdgcn_mfma_f32_16x16x32_bf16(a, b1, c1[mt], 0, 0, 0);
      c2[mt] = __builtin_amdgcn_mfma_f32_16x16x32_bf16(a, b2, c2[mt], 0, 0, 0);
    }
  }
#pragma unroll
  for (int mt = 0; mt < 2; ++mt)
#pragma unroll
    for (int rr = 0; rr < 4; ++rr) {
      float den = __shfl(c2[mt][rr], lane & 48);
      int rowl = tw + mt * 16 + lq * 4 + rr;
      float inv = 1.f / den;
      ao[(size_t)rowl * 256 + head * 32 + lr] = f2bf(c0[mt][rr] * inv);
      ao[(size_t)rowl * 256 + head * 32 + 16 + lr] = f2bf(c1[mt][rr] * inv);
    }
}

// ================= mean pool + final FC (fp32 h) =================
__global__ __launch_bounds__(256) void pool_kernel(
    const float* __restrict__ h, float* __restrict__ pooled) {
  int b = blockIdx.x, chunk = blockIdx.y, j = threadIdx.x;
  const float* hp = h + (size_t)(b * D_S + chunk * 256) * 256 + j;
  float acc = 0.f;
#pragma unroll 4
  for (int s = 0; s < 256; ++s) acc += hp[(size_t)s * 256];
  atomicAdd(pooled + b * 256 + j, acc);
}

__global__ __launch_bounds__(64) void final_kernel(
    const float* __restrict__ pooled, const float* __restrict__ fcw,
    const float* __restrict__ fcb, float* __restrict__ out) {
  int tid = threadIdx.x;
  if (tid >= 16) return;
  int b = tid >> 1, c = tid & 1;
  float acc = 0.f;
  for (int j = 0; j < 256; ++j) acc += pooled[b * 256 + j] * fcw[j * 2 + c];
  out[b * 2 + c] = acc * (1.f / 8192.f) + fcb[c];
}

extern "C" void kernel_launch(void* const* d_in, const int* in_sizes, int n_in,
                              void* d_out, int out_size, void* d_ws, size_t ws_size,
                              hipStream_t stream) {
  const float* x     = (const float*)d_in[0];
  const float* emb_w = (const float*)d_in[1];
  const float* emb_b = (const float*)d_in[2];
  const float* pos   = (const float*)d_in[3];
  const float* ln1_g = (const float*)d_in[4];
  const float* ln1_b = (const float*)d_in[5];
  const float* wq    = (const float*)d_in[6];
  const float* wk    = (const float*)d_in[7];
  const float* wv    = (const float*)d_in[8];
  const float* wo    = (const float*)d_in[9];
  const float* bo    = (const float*)d_in[10];
  const float* ln2_g = (const float*)d_in[11];
  const float* ln2_b = (const float*)d_in[12];
  const float* w1    = (const float*)d_in[13];
  const float* b1    = (const float*)d_in[14];
  const float* w2    = (const float*)d_in[15];
  const float* b2    = (const float*)d_in[16];
  const float* proj  = (const float*)d_in[17];
  const float* fc_w  = (const float*)d_in[18];
  const float* fc_b  = (const float*)d_in[19];

  if (ws_size < NEED_BYTES) {
    report_kernel<<<1, 64, 0, stream>>>((float*)d_out, (float)ws_size);
    return;
  }

  float* ws = (float*)d_ws;
  float* h      = ws + OFF_H;
  u16* xnb      = (u16*)(ws + OFF_XNB);
  u16* BIG      = (u16*)(ws + OFF_BIG);
  u16* Vb       = (u16*)(ws + OFF_V);
  u16* WKPt     = (u16*)(ws + OFF_WKP);
  u16* WQPt     = (u16*)(ws + OFF_WQP);
  u16* WKt      = (u16*)(ws + OFF_WK);
  u16* WQt      = (u16*)(ws + OFF_WQ);
  u16* WVt      = (u16*)(ws + OFF_WV);
  u16* WOt      = (u16*)(ws + OFF_WO);
  u16* W1t      = (u16*)(ws + OFF_W1);
  u16* W2t      = (u16*)(ws + OFF_W2);
  u16* dg       = (u16*)(ws + OFF_DG);
  unsigned int* kmaxk = (unsigned int*)(ws + OFF_KMAX);
  float* part   = ws + OFF_PART;
  u16* Bt       = (u16*)(ws + OFF_PART);  // reuses part after ctxreduce (btprep reads ctx/ksum only)
  float* partk  = ws + OFF_PARTK;
  float* ctx    = ws + OFF_CTX;
  float* ksum   = ws + OFF_KSUM;
  float* pooled = ws + OFF_POOL;

  // ---- embed as MFMA GEMM ----
  xcvt_kernel<<<4096, 256, 0, stream>>>(x, BIG);
  wsplit_kernel<<<64, 256, 0, stream>>>(emb_w, WKPt, 64, 256, 8);
  mfma_gemm<4, 0, 0, 0, 2><<<dim3(512, 2), 256, 0, stream>>>(
      BIG, WKPt, nullptr, emb_b, pos, nullptr, h, nullptr, nullptr, nullptr, 256, 64);

  for (int l = 0; l < D_L; ++l) {
    const float* pj = proj + l * 2048;
    ln_kernel<<<TOK / 4, 256, 0, stream>>>(h, xnb, ln1_g + l * 256, ln1_b + l * 256);
    wprep_kernel<<<4096, 256, 0, stream>>>(
        wk + l * 65536, wq + l * 65536, wv + l * 65536, wo + l * 65536,
        w1 + l * 262144, w2 + l * 262144, pj,
        WKPt, WQPt, WKt, WQt, WVt, WOt, W1t, W2t, kmaxk);

    // fused xp(+kmax) and diag(k|q): one launch, y<4 xp / y>=4 diag
    mfma_gemm<6, 0, 0, 1, 1><<<dim3(512, 8), 256, 0, stream>>>(
        xnb, WKPt, WKt, nullptr, nullptr, nullptr, nullptr, BIG, dg, kmaxk, 512, 256);
    // context accumulation per half (exp fused into staging)
    for (int hf = 0; hf < 2; ++hf) {
      const u16* xh = xnb + (size_t)hf * 32768 * 256;
      mfma_gemm<0, 0, 0, 1, 1><<<dim3(256, 2), 256, 0, stream>>>(
          xh, WVt, nullptr, nullptr, nullptr, nullptr, nullptr, Vb, nullptr, nullptr, 256, 256);
      ctxaccum_kernel<<<dim3(32, 16), 256, 0, stream>>>(BIG, Vb, dg, kmaxk, part, partk, hf);
    }
    ctxreduce_kernel<<<64, 256, 0, stream>>>(part, partk, ctx, ksum);
    btprep_kernel<<<64, 256, 0, stream>>>(ctx, ksum, Bt);
    // qp (overwrites BIG; xp dead), single-plane WQP
    mfma_gemm<3, 0, 0, 1, 1><<<dim3(512, 4), 256, 0, stream>>>(
        xnb, WQPt, nullptr, nullptr, nullptr, dg, nullptr, BIG, nullptr, nullptr, 512, 256);
    for (int hf = 0; hf < 2; ++hf) {
      float* hh = h + (size_t)hf * 32768 * 256;
      attnout_kernel<<<dim3(256, 8), 256, 0, stream>>>(BIG, Bt, Vb, hf);
      mfma_gemm<0, 0, 1, 0, 1><<<dim3(256, 2), 256, 0, stream>>>(
          Vb, WOt, nullptr, bo + l * 256, nullptr, nullptr, hh, nullptr, nullptr, nullptr, 256, 256);
    }

    ln_kernel<<<TOK / 4, 256, 0, stream>>>(h, xnb, ln2_g + l * 256, ln2_b + l * 256);
    for (int hf = 0; hf < 2; ++hf) {
      const u16* xh = xnb + (size_t)hf * 32768 * 256;
      float* hh = h + (size_t)hf * 32768 * 256;
      // FFN single-plane bf16 (KM=1)
      mfma_gemm<0, 1, 0, 1, 1><<<dim3(256, 8), 256, 0, stream>>>(
          xh, W1t, nullptr, b1 + l * 1024, nullptr, nullptr, nullptr, BIG, nullptr, nullptr, 1024, 256);
      mfma_gemm<0, 0, 1, 0, 1><<<dim3(256, 2), 256, 0, stream>>>(
          BIG, W2t, nullptr, b2 + l * 256, nullptr, nullptr, hh, nullptr, nullptr, nullptr, 256, 1024);
    }
  }

  zero_kernel<<<8, 256, 0, stream>>>(pooled, 2048);
  pool_kernel<<<dim3(8, 32), 256, 0, stream>>>(h, pooled);
  final_kernel<<<1, 64, 0, stream>>>(pooled, fc_w, fc_b, (float*)d_out);
}

// Round 14
// 2109.159 us; speedup vs baseline: 1.0271x; 1.0078x over previous
//
#include <hip/hip_runtime.h>
#include <math.h>

typedef unsigned short u16;
typedef __attribute__((ext_vector_type(8))) short bf16x8;
typedef __attribute__((ext_vector_type(4))) float f32x4;

// ---- problem dims ----
static constexpr int D_S = 8192;
static constexpr int D_L = 4;
static constexpr int TOK = 65536;
static constexpr float NORMALIZER = 0.4204482076268573f;  // 32^-0.25
static constexpr float RATIO = 0.125f;                    // 64^-0.5
static constexpr float KEPS = 1e-4f;

// ---- workspace layout (float slots) ----
static constexpr size_t OFF_H     = 0;
static constexpr size_t OFF_XNB   = 16777216;
static constexpr size_t OFF_BIG   = 25165824;
static constexpr size_t OFF_V     = 41943040;
static constexpr size_t OFF_WKP   = 46137344;
static constexpr size_t OFF_WQP   = 46268416;
static constexpr size_t OFF_WK    = 46399488;
static constexpr size_t OFF_WQ    = 46465024;
static constexpr size_t OFF_WV    = 46530560;
static constexpr size_t OFF_WO    = 46596096;
static constexpr size_t OFF_W1    = 46661632;
static constexpr size_t OFF_W2    = 46923776;
static constexpr size_t OFF_DG    = 47185920;
static constexpr size_t OFF_KMAX  = 47710208;
static constexpr size_t OFF_PART  = 47710272;
static constexpr size_t OFF_PARTK = 49807424;
static constexpr size_t OFF_CTX   = 49872960;
static constexpr size_t OFF_KSUM  = 50004032;
static constexpr size_t OFF_POOL  = 50008128;
static constexpr size_t NEED_BYTES = 200040704;

static constexpr int BTS = 136;  // Bt row stride in u16 (128 + 8 pad)

static __device__ __forceinline__ float bf2f(u16 u) {
  return __uint_as_float(((unsigned int)u) << 16);
}
static __device__ __forceinline__ u16 f2bf(float f) {
  unsigned int u = __float_as_uint(f);
  u = (u + 0x7fffu + ((u >> 16) & 1u)) >> 16;
  return (u16)u;
}
static __device__ __forceinline__ float geluf(float v) {
  return 0.5f * v * (1.f + erff(v * 0.70710678118654752f));
}
static __device__ __forceinline__ float dec_max(unsigned int mk) {
  return __uint_as_float((mk & 0x80000000u) ? (mk & 0x7fffffffu) : ~mk);
}

// async global->LDS, 16B per lane; dest = wave-uniform base + lane*16 (m97 pattern)
static __device__ __forceinline__ void gload16(const u16* g, u16* l) {
  __builtin_amdgcn_global_load_lds(
      (const __attribute__((address_space(1))) unsigned int*)g,
      (__attribute__((address_space(3))) unsigned int*)l, 16, 0, 0);
}

__global__ void report_kernel(float* out, float v) {
  if (threadIdx.x < 16) out[threadIdx.x] = v;
}

__global__ __launch_bounds__(256) void zero_kernel(float* p, int n) {
  int i = blockIdx.x * 256 + threadIdx.x;
  if (i < n) p[i] = 0.f;
}

// ================= x -> bf16 =================
__global__ __launch_bounds__(256) void xcvt_kernel(const float* __restrict__ x,
                                                   u16* __restrict__ xb) {
  int i4 = (blockIdx.x * 256 + threadIdx.x) * 4;
  float4 v = *(const float4*)(x + i4);
  u16 o[4] = {f2bf(v.x), f2bf(v.y), f2bf(v.z), f2bf(v.w)};
  *(uint2*)(xb + i4) = *(uint2*)o;
}

// ================= layernorm: fp32 in, bf16 out =================
__global__ __launch_bounds__(256) void ln_kernel(
    const float* __restrict__ src, u16* __restrict__ dst,
    const float* __restrict__ g, const float* __restrict__ b) {
  int wv = threadIdx.x >> 6, lane = threadIdx.x & 63;
  int t = blockIdx.x * 4 + wv;
  const float4 v = *(const float4*)(src + (size_t)t * 256 + lane * 4);
  float s1 = v.x + v.y + v.z + v.w;
  float s2 = v.x * v.x + v.y * v.y + v.z * v.z + v.w * v.w;
  for (int off = 32; off; off >>= 1) {
    s1 += __shfl_xor(s1, off);
    s2 += __shfl_xor(s2, off);
  }
  float mu = s1 * (1.f / 256.f);
  float var = s2 * (1.f / 256.f) - mu * mu;
  float rs = rsqrtf(var + 1e-5f);
  float4 gg = *(const float4*)(g + lane * 4);
  float4 bb = *(const float4*)(b + lane * 4);
  u16 o0 = f2bf((v.x - mu) * rs * gg.x + bb.x);
  u16 o1 = f2bf((v.y - mu) * rs * gg.y + bb.y);
  u16 o2 = f2bf((v.z - mu) * rs * gg.z + bb.z);
  u16 o3 = f2bf((v.w - mu) * rs * gg.w + bb.w);
  uint2 pk;
  pk.x = (unsigned)o0 | ((unsigned)o1 << 16);
  pk.y = (unsigned)o2 | ((unsigned)o3 << 16);
  *(uint2*)(dst + (size_t)t * 256 + lane * 4) = pk;
}

// ===== embed weight split (hi/lo), used once pre-loop =====
__global__ __launch_bounds__(256) void wsplit_kernel(
    const float* __restrict__ W, u16* __restrict__ Wt, int K, int N, int nb) {
  int i = blockIdx.x * 256 + threadIdx.x;
  int k = i >> nb, n = i & (N - 1);
  float val = W[i];
  u16 hi = f2bf(val);
  u16 lo = f2bf(val - bf2f(hi));
  Wt[(size_t)n * 2 * K + k] = hi;
  Wt[(size_t)n * 2 * K + K + k] = lo;
}

// ===== merged per-layer weight prep (all single-plane except embed) =====
__global__ __launch_bounds__(256) void wprep_kernel(
    const float* __restrict__ wk, const float* __restrict__ wq,
    const float* __restrict__ wv, const float* __restrict__ wo,
    const float* __restrict__ w1, const float* __restrict__ w2,
    const float* __restrict__ proj,
    u16* __restrict__ WKP, u16* __restrict__ WQP,
    u16* __restrict__ WKt, u16* __restrict__ WQt,
    u16* __restrict__ WVt, u16* __restrict__ WOt,
    u16* __restrict__ W1t, u16* __restrict__ W2t,
    unsigned int* __restrict__ kmaxk) {
  int gi = blockIdx.x * 256 + threadIdx.x;
  if (gi < 64) kmaxk[gi] = 0u;
  if (gi < 262144) {  // WKP / WQP: proj-folded single-plane
    int i = gi & 131071;
    const float* w = (gi < 131072) ? wk : wq;
    u16* Wt = (gi < 131072) ? WKP : WQP;
    int k = i & 255, n = i >> 8;
    int head = n >> 6, m = n & 63;
    float s = 0.f;
#pragma unroll
    for (int d = 0; d < 32; ++d) s += w[k * 256 + head * 32 + d] * proj[m * 32 + d];
    Wt[(size_t)n * 256 + k] = f2bf(s * NORMALIZER);
  } else if (gi < 393216) {  // WKt / WQt single-plane
    int i = gi - 262144;
    const float* W = (i < 65536) ? wk : wq;
    u16* T = (i < 65536) ? WKt : WQt;
    int j = i & 65535;
    int k = j >> 8, n = j & 255;
    T[(size_t)n * 256 + k] = f2bf(W[j]);
  } else if (gi < 524288) {  // WVt / WOt single-plane
    int i = gi - 393216;
    const float* W = (i < 65536) ? wv : wo;
    u16* T = (i < 65536) ? WVt : WOt;
    int j = i & 65535;
    int k = j >> 8, n = j & 255;
    T[(size_t)n * 256 + k] = f2bf(W[j]);
  } else if (gi < 786432) {  // W1 single-plane: K=256, N=1024
    int i = gi - 524288;
    int k = i >> 10, n = i & 1023;
    W1t[(size_t)n * 256 + k] = f2bf(w1[i]);
  } else {                   // W2 single-plane: K=1024, N=256
    int i = gi - 786432;
    int k = i >> 8, n = i & 255;
    W2t[(size_t)n * 1024 + k] = f2bf(w2[i]);
  }
}

// ================= MFMA GEMM: 128x128 tile, A bf16 [M][K], Wt bf16 [N][K*KM] =================
// KM=2: hi/lo split weights; KM=1: single-plane.
// T1 XCD swizzle (bijective), y-fastest -> A-panel L2 reuse per XCD.
// Staging: gload_lds width=16, FOUR 32-k buffers processed in PAIRS (BK=64 effective):
//   prologue stages 4 bufs (16 loads in flight); each phase waits vmcnt(8) (own pair
//   landed, next pair's 8 loads fly ACROSS the barrier), computes 32 MFMAs (buf pair),
//   lgkm-drains, barriers, restages the just-read pair 2 phases ahead. Tail vmcnt(0).
//   Halves barrier crossings vs r10; buffer layout/swizzle/read addressing unchanged.
// T5: s_setprio(1) around each MFMA cluster.
// Chunk swizzle (both-sides, rule 21): LDS slot(row,q') = row*4 + q' holds global k-chunk
// q = q' ^ ((row>>1)&3); fragment reads same XOR -> 2-way bank (free, m136).
// EPI: 0 plain (ACT gelu, ACC fp32-acc, OBF bf16 store), 3 qp, 4 embed,
//      6 fused xp(y<4: store+max over Wt)+diag(y>=4: over Wt2)
template <int EPI, int ACT, int ACC, int OBF, int KM>
__global__ __launch_bounds__(256) void mfma_gemm(
    const u16* __restrict__ A, const u16* __restrict__ Wt,
    const u16* __restrict__ Wt2,
    const float* __restrict__ bias, const float* __restrict__ posP,
    const u16* __restrict__ diagIn,
    float* __restrict__ outF, u16* __restrict__ outB,
    u16* __restrict__ diagOut, unsigned int* __restrict__ kmaxOut,
    int N, int K) {
  __shared__ __align__(16) u16 Als[16384];  // 4 bufs x 512 slots x 8 u16 (32KB)
  __shared__ __align__(16) u16 Bls[16384];
  const int K2 = K * KM;
  int tid = threadIdx.x;
  // ---- T1 bijective XCD swizzle, y-fastest work order ----
  int tot = gridDim.x * gridDim.y;
  int f = blockIdx.x + gridDim.x * blockIdx.y;
  int wid = (f & 7) * (tot >> 3) + (f >> 3);
  int ny = gridDim.y;                       // power of 2 (2,4,8)
  int lg = 31 - __clz(ny);
  int xb = wid >> lg;
  int yb = wid & (ny - 1);
  int bm = xb * 128;
  const u16* Wp = Wt;
  int bn = yb * 128;
  if (EPI == 6 && yb >= 4) { Wp = Wt2; bn = (yb - 4) * 128; }
  int w = tid >> 6, lane = tid & 63;
  int wm = w >> 1, wn = w & 1;
  int lr = lane & 15, lq = lane >> 4;
  f32x4 acc[4][4];
#pragma unroll
  for (int i = 0; i < 4; ++i)
#pragma unroll
    for (int j = 0; j < 4; ++j) acc[i][j] = (f32x4){0.f, 0.f, 0.f, 0.f};
  // staging lane geometry (see header comment)
  int sub = lane >> 2;                         // row within 16-row group
  int qsw = (lane & 3) ^ ((lane >> 3) & 3);    // global k-chunk this lane fetches
  const u16* gA0 = A + (size_t)(bm + 32 * w + sub) * K + qsw * 8;
  const u16* gA1 = gA0 + (size_t)16 * K;
  const u16* gB0 = Wp + (size_t)(bn + 32 * w + sub) * K2 + qsw * 8;
  const u16* gB1 = gB0 + (size_t)16 * K2;
  u16* lA0 = Als + (w * 2 + 0) * 512;          // wave-uniform LDS bases (slot*8 u16)
  u16* lA1 = Als + (w * 2 + 1) * 512;
  u16* lB0 = Bls + (w * 2 + 0) * 512;
  u16* lB1 = Bls + (w * 2 + 1) * 512;
  // fragment read base (chunk swizzle folded in; per-lane constant)
  int qswr = lq ^ ((lr >> 1) & 3);
  int aB = wm * 256 + lr * 4 + qswr;
  int bB = wn * 256 + lr * 4 + qswr;

#define STAGE(buf, kk) do { \
    int ka_ = (kk) & (K - 1); int kb_ = (kk); int lo_ = (buf) * 4096; \
    gload16(gA0 + ka_, lA0 + lo_); \
    gload16(gA1 + ka_, lA1 + lo_); \
    gload16(gB0 + kb_, lB0 + lo_); \
    gload16(gB1 + kb_, lB1 + lo_); \
  } while (0)

#define FRAGMMA(buf) do { \
    const bf16x8* Ab_ = (const bf16x8*)(Als + (buf) * 4096); \
    const bf16x8* Bb_ = (const bf16x8*)(Bls + (buf) * 4096); \
    bf16x8 af_[4], bfr_[4]; \
    _Pragma("unroll") \
    for (int mi = 0; mi < 4; ++mi) af_[mi] = Ab_[aB + mi * 64]; \
    _Pragma("unroll") \
    for (int ni = 0; ni < 4; ++ni) bfr_[ni] = Bb_[bB + ni * 64]; \
    __builtin_amdgcn_s_setprio(1); \
    _Pragma("unroll") \
    for (int mi = 0; mi < 4; ++mi) \
      _Pragma("unroll") \
      for (int ni = 0; ni < 4; ++ni) \
        acc[mi][ni] = __builtin_amdgcn_mfma_f32_16x16x32_bf16(af_[mi], bfr_[ni], acc[mi][ni], 0, 0, 0); \
    __builtin_amdgcn_s_setprio(0); \
  } while (0)

  const int np = K2 / 64;                      // pairs; >= 2 for all instantiations
  STAGE(0, 0);
  STAGE(1, 32);
  STAGE(2, 64);
  STAGE(3, 96);
  for (int p = 0; p < np; ++p) {
    int b0 = (p & 1) * 2;                      // bufs (0,1) / (2,3)
    if (p + 1 < np) asm volatile("s_waitcnt vmcnt(8)" ::: "memory");
    else            asm volatile("s_waitcnt vmcnt(0)" ::: "memory");
    __builtin_amdgcn_s_barrier();              // all waves' pair loads landed
    __builtin_amdgcn_sched_barrier(0);         // pin: no ds_read above barrier1
    FRAGMMA(b0);
    FRAGMMA(b0 + 1);
    asm volatile("s_waitcnt lgkmcnt(0)" ::: "memory");  // my ds_reads complete
    __builtin_amdgcn_sched_barrier(0);
    __builtin_amdgcn_s_barrier();              // all waves done reading this pair
    __builtin_amdgcn_sched_barrier(0);         // pin: STAGE stays below barrier2
    if (p + 2 < np) {
      STAGE(b0, (p + 2) * 64);
      STAGE(b0 + 1, (p + 2) * 64 + 32);
    }
  }
#undef FRAGMMA
#undef STAGE
  // ---- epilogues ----  C/D: col = lane&15, row = (lane>>4)*4 + r  [m89-verified]
  if (EPI == 0) {
#pragma unroll
    for (int ni = 0; ni < 4; ++ni) {
      int col = bn + wn * 64 + ni * 16 + lr;
      float bv = bias ? bias[col] : 0.f;
#pragma unroll
      for (int mi = 0; mi < 4; ++mi)
#pragma unroll
        for (int rr = 0; rr < 4; ++rr) {
          int rowg = bm + wm * 64 + mi * 16 + lq * 4 + rr;
          float val = acc[mi][ni][rr] + bv;
          if (ACT) val = geluf(val);
          size_t o = (size_t)rowg * N + col;
          if (OBF) outB[o] = f2bf(val);
          else if (ACC) outF[o] += val;
          else outF[o] = val;
        }
    }
  }
  if (EPI == 3) {  // qp: in-wave row-max over the head's 64 cols, then exp; dg q-heads at +8
    int head = (bn + wn * 64) >> 6;
#pragma unroll
    for (int mi = 0; mi < 4; ++mi) {
      float rm[4] = {-3.4e38f, -3.4e38f, -3.4e38f, -3.4e38f};
#pragma unroll
      for (int ni = 0; ni < 4; ++ni)
#pragma unroll
        for (int rr = 0; rr < 4; ++rr) rm[rr] = fmaxf(rm[rr], acc[mi][ni][rr]);
#pragma unroll
      for (int rr = 0; rr < 4; ++rr) {
        float t = rm[rr];
        t = fmaxf(t, __shfl_xor(t, 1)); t = fmaxf(t, __shfl_xor(t, 2));
        t = fmaxf(t, __shfl_xor(t, 4)); t = fmaxf(t, __shfl_xor(t, 8));
        rm[rr] = t;
      }
#pragma unroll
      for (int rr = 0; rr < 4; ++rr) {
        int rowg = bm + wm * 64 + mi * 16 + lq * 4 + rr;
        float dgv = bf2f(diagIn[(size_t)rowg * 16 + 8 + head]);
#pragma unroll
        for (int ni = 0; ni < 4; ++ni) {
          int col = bn + wn * 64 + ni * 16 + lr;
          float v = RATIO * (__expf(acc[mi][ni][rr] - dgv - rm[rr]) + KEPS);
          outB[(size_t)rowg * N + col] = f2bf(v);
        }
      }
    }
  }
  if (EPI == 4) {  // embed: + bias + pos, fp32 store (N==256)
#pragma unroll
    for (int ni = 0; ni < 4; ++ni) {
      int col = bn + wn * 64 + ni * 16 + lr;
      float bv = bias[col];
#pragma unroll
      for (int mi = 0; mi < 4; ++mi)
#pragma unroll
        for (int rr = 0; rr < 4; ++rr) {
          int rowg = bm + wm * 64 + mi * 16 + lq * 4 + rr;
          outF[(size_t)rowg * 256 + col] =
              acc[mi][ni][rr] + bv + posP[(size_t)(rowg & (D_S - 1)) * 256 + col];
        }
    }
  }
  if (EPI == 6) {
    if (yb < 4) {  // xp: store bf16 + global max per (b, head)
      float mx = -3.4e38f;
#pragma unroll
      for (int mi = 0; mi < 4; ++mi)
#pragma unroll
        for (int ni = 0; ni < 4; ++ni)
#pragma unroll
          for (int rr = 0; rr < 4; ++rr) {
            float v = acc[mi][ni][rr];
            mx = fmaxf(mx, v);
            int rowg = bm + wm * 64 + mi * 16 + lq * 4 + rr;
            int col = bn + wn * 64 + ni * 16 + lr;
            outB[(size_t)rowg * N + col] = f2bf(v);
          }
#pragma unroll
      for (int off = 1; off < 64; off <<= 1) mx = fmaxf(mx, __shfl_xor(mx, off));
      if (lane == 0) {
        int b = bm >> 13;
        int head = (bn + wn * 64) >> 6;
        unsigned int u = __float_as_uint(mx);
        unsigned int key = (u & 0x80000000u) ? ~u : (u | 0x80000000u);
        atomicMax(kmaxOut + b * 8 + head, key);
      }
    } else {  // diag per head (32 cols); wave spans 2 heads; dg layout [t][16]
      const float c05n2 = 0.5f * NORMALIZER * NORMALIZER;
      int hb = (bn + wn * 64) >> 5;
#pragma unroll
      for (int mi = 0; mi < 4; ++mi) {
        float s0[4] = {0.f, 0.f, 0.f, 0.f}, s1[4] = {0.f, 0.f, 0.f, 0.f};
#pragma unroll
        for (int ni = 0; ni < 4; ++ni)
#pragma unroll
          for (int rr = 0; rr < 4; ++rr) {
            float v = acc[mi][ni][rr];
            if (ni < 2) s0[rr] += v * v; else s1[rr] += v * v;
          }
#pragma unroll
        for (int rr = 0; rr < 4; ++rr) {
          float a = s0[rr], b = s1[rr];
          a += __shfl_xor(a, 1); a += __shfl_xor(a, 2); a += __shfl_xor(a, 4); a += __shfl_xor(a, 8);
          b += __shfl_xor(b, 1); b += __shfl_xor(b, 2); b += __shfl_xor(b, 4); b += __shfl_xor(b, 8);
          if (lr == 0) {
            int rowg = bm + wm * 64 + mi * 16 + lq * 4 + rr;
            diagOut[(size_t)rowg * 16 + hb] = f2bf(c05n2 * a);
            diagOut[(size_t)rowg * 16 + hb + 1] = f2bf(c05n2 * b);
          }
        }
      }
    }
  }
}

// ===== ctxaccum: kp computed inline from raw xp (exp fused); part[m][e] = sum kp*v =====
__global__ __launch_bounds__(256) void ctxaccum_kernel(
    const u16* __restrict__ xp, const u16* __restrict__ v,
    const u16* __restrict__ dg, const unsigned int* __restrict__ kmaxk,
    float* __restrict__ part, float* __restrict__ partk, int hf) {
  __shared__ float kpS[64 * 64];
  __shared__ float vS[64 * 32];
  int tid = threadIdx.x;
  int bl = blockIdx.x >> 3, head = blockIdx.x & 7, c = blockIdx.y;
  int n0l = bl * 8192 + c * 512;   // within half (32768 tokens)
  int bhg = (hf * 4 + bl) * 8 + head;
  int tg0 = hf * 32768 + n0l;
  float mx = dec_max(kmaxk[bhg]);
  int m = tid & 63, eg = tid >> 6;
  float acc[8] = {};
  float ks = 0.f;
  const u16* kpb = xp + (size_t)tg0 * 512 + head * 64;
  const u16* vb = v + (size_t)n0l * 256 + head * 32;
  for (int tile = 0; tile < 8; ++tile) {
    int nb = tile * 64;
    __syncthreads();
#pragma unroll
    for (int i = 0; i < 2; ++i) {
      int idx8 = tid + i * 256;          // 512 chunks of 8
      int row = idx8 >> 3, c8 = (idx8 & 7) * 8;
      float dgrow = bf2f(dg[(size_t)(tg0 + nb + row) * 16 + head]);
      u16 tmp[8];
      *(uint4*)tmp = *(const uint4*)(kpb + (size_t)(nb + row) * 512 + c8);
#pragma unroll
      for (int j = 0; j < 8; ++j)
        kpS[row * 64 + c8 + j] = RATIO * (__expf(bf2f(tmp[j]) - dgrow - mx) + KEPS);
    }
    {
      int row = tid >> 2, c8 = (tid & 3) * 8;
      u16 tmp[8];
      *(uint4*)tmp = *(const uint4*)(vb + (size_t)(nb + row) * 256 + c8);
#pragma unroll
      for (int j = 0; j < 8; ++j) vS[row * 32 + c8 + j] = bf2f(tmp[j]);
    }
    __syncthreads();
#pragma unroll 4
    for (int n = 0; n < 64; ++n) {
      float kv = kpS[n * 64 + m];
      if (eg == 0) ks += kv;
      const float* vr = &vS[n * 32 + eg * 8];
#pragma unroll
      for (int j = 0; j < 8; ++j) acc[j] += kv * vr[j];
    }
  }
  float* pp = part + ((size_t)bhg * 16 + c) * 2048 + m * 32 + eg * 8;
#pragma unroll
  for (int j = 0; j < 8; ++j) pp[j] = acc[j];
  if (eg == 0) partk[((size_t)bhg * 16 + c) * 64 + m] = ks;
}

__global__ __launch_bounds__(256) void ctxreduce_kernel(
    const float* __restrict__ part, const float* __restrict__ partk,
    float* __restrict__ ctx, float* __restrict__ ksum) {
  int bh = blockIdx.x, tid = threadIdx.x;
#pragma unroll
  for (int i = 0; i < 8; ++i) {
    int idx = tid + i * 256;
    float s = 0.f;
#pragma unroll
    for (int cc = 0; cc < 16; ++cc)
      s += part[((size_t)bh * 16 + cc) * 2048 + idx];
    ctx[(size_t)bh * 2048 + idx] = s;
  }
  if (tid < 64) {
    float s = 0.f;
#pragma unroll
    for (int cc = 0; cc < 16; ++cc) s += partk[((size_t)bh * 16 + cc) * 64 + tid];
    ksum[bh * 64 + tid] = s;
  }
}

// ===== btprep: pack [ctx | ksum | 0] into B-operand hi/lo bf16: Bt[bh][48][BTS] =====
__global__ __launch_bounds__(256) void btprep_kernel(
    const float* __restrict__ ctx, const float* __restrict__ ksum,
    u16* __restrict__ Bt) {
  int bh = blockIdx.x, tid = threadIdx.x;
  for (int idx = tid; idx < 48 * 64; idx += 256) {
    int n = idx >> 6, k = idx & 63;
    float v = 0.f;
    if (n < 32) v = ctx[(size_t)bh * 2048 + k * 32 + n];
    else if (n == 32) v = ksum[bh * 64 + k];
    u16 hi = f2bf(v);
    u16 lo = f2bf(v - bf2f(hi));
    u16* row = Bt + ((size_t)bh * 48 + n) * BTS;
    row[k] = hi;
    row[64 + k] = lo;
  }
}

// ===== attnout via MFMA: ao = (qp@ctx)/(qp@ksum) =====
__global__ __launch_bounds__(256) void attnout_kernel(
    const u16* __restrict__ qp, const u16* __restrict__ Bt,
    u16* __restrict__ ao, int hf) {
  __shared__ __align__(16) u16 BtS[48 * BTS];
  int tid = threadIdx.x;
  int rb = blockIdx.x, head = blockIdx.y;
  int t0l = rb * 128;
  int bhg = ((hf * 32768 + t0l) >> 13) * 8 + head;
  {
    const uint4* src = (const uint4*)(Bt + (size_t)bhg * 48 * BTS);
    for (int i = tid; i < 48 * BTS / 8; i += 256) ((uint4*)BtS)[i] = src[i];
  }
  __syncthreads();
  int w = tid >> 6, lane = tid & 63;
  int lr = lane & 15, lq = lane >> 4;
  int tw = t0l + w * 32;
  const u16* qpb = qp + (size_t)(hf * 32768 + tw) * 512 + head * 64;
  bf16x8 af[2][2];
#pragma unroll
  for (int mt = 0; mt < 2; ++mt)
#pragma unroll
    for (int kc = 0; kc < 2; ++kc)
      af[mt][kc] = *(const bf16x8*)(qpb + (size_t)(mt * 16 + lr) * 512 + kc * 32 + lq * 8);
  f32x4 c0[2], c1[2], c2[2];
#pragma unroll
  for (int mt = 0; mt < 2; ++mt) {
    c0[mt] = (f32x4){0.f, 0.f, 0.f, 0.f};
    c1[mt] = (f32x4){0.f, 0.f, 0.f, 0.f};
    c2[mt] = (f32x4){0.f, 0.f, 0.f, 0.f};
  }
#pragma unroll
  for (int kc = 0; kc < 4; ++kc) {
    bf16x8 b0 = *(const bf16x8*)(BtS + (size_t)(0 * 16 + lr) * BTS + kc * 32 + lq * 8);
    bf16x8 b1 = *(const bf16x8*)(BtS + (size_t)(1 * 16 + lr) * BTS + kc * 32 + lq * 8);
    bf16x8 b2 = *(const bf16x8*)(BtS + (size_t)(2 * 16 + lr) * BTS + kc * 32 + lq * 8);
#pragma unroll
    for (int mt = 0; mt < 2; ++mt) {
      bf16x8 a = af[mt][kc & 1];
      c0[mt] = __builtin_amdgcn_mfma_f32_16x16x32_bf16(a, b0, c0[mt], 0, 0, 0);
      c1[mt] = __builtin_amdgcn_mfma_f32_16x16x32_bf16(a, b1, c1[mt], 0, 0, 0);
      c2[mt] = __builtin_amdgcn_mfma_f32_16x16x32_bf16(a, b2, c2[mt], 0, 0, 0);
    }
  }
#pragma unroll
  for (int mt = 0; mt < 2; ++mt)
#pragma unroll
    for (int rr = 0; rr < 4; ++rr) {
      float den = __shfl(c2[mt][rr], lane & 48);
      int rowl = tw + mt * 16 + lq * 4 + rr;
      float inv = 1.f / den;
      ao[(size_t)rowl * 256 + head * 32 + lr] = f2bf(c0[mt][rr] * inv);
      ao[(size_t)rowl * 256 + head * 32 + 16 + lr] = f2bf(c1[mt][rr] * inv);
    }
}

// ================= mean pool + final FC (fp32 h) =================
__global__ __launch_bounds__(256) void pool_kernel(
    const float* __restrict__ h, float* __restrict__ pooled) {
  int b = blockIdx.x, chunk = blockIdx.y, j = threadIdx.x;
  const float* hp = h + (size_t)(b * D_S + chunk * 256) * 256 + j;
  float acc = 0.f;
#pragma unroll 4
  for (int s = 0; s < 256; ++s) acc += hp[(size_t)s * 256];
  atomicAdd(pooled + b * 256 + j, acc);
}

__global__ __launch_bounds__(64) void final_kernel(
    const float* __restrict__ pooled, const float* __restrict__ fcw,
    const float* __restrict__ fcb, float* __restrict__ out) {
  int tid = threadIdx.x;
  if (tid >= 16) return;
  int b = tid >> 1, c = tid & 1;
  float acc = 0.f;
  for (int j = 0; j < 256; ++j) acc += pooled[b * 256 + j] * fcw[j * 2 + c];
  out[b * 2 + c] = acc * (1.f / 8192.f) + fcb[c];
}

extern "C" void kernel_launch(void* const* d_in, const int* in_sizes, int n_in,
                              void* d_out, int out_size, void* d_ws, size_t ws_size,
                              hipStream_t stream) {
  const float* x     = (const float*)d_in[0];
  const float* emb_w = (const float*)d_in[1];
  const float* emb_b = (const float*)d_in[2];
  const float* pos   = (const float*)d_in[3];
  const float* ln1_g = (const float*)d_in[4];
  const float* ln1_b = (const float*)d_in[5];
  const float* wq    = (const float*)d_in[6];
  const float* wk    = (const float*)d_in[7];
  const float* wv    = (const float*)d_in[8];
  const float* wo    = (const float*)d_in[9];
  const float* bo    = (const float*)d_in[10];
  const float* ln2_g = (const float*)d_in[11];
  const float* ln2_b = (const float*)d_in[12];
  const float* w1    = (const float*)d_in[13];
  const float* b1    = (const float*)d_in[14];
  const float* w2    = (const float*)d_in[15];
  const float* b2    = (const float*)d_in[16];
  const float* proj  = (const float*)d_in[17];
  const float* fc_w  = (const float*)d_in[18];
  const float* fc_b  = (const float*)d_in[19];

  if (ws_size < NEED_BYTES) {
    report_kernel<<<1, 64, 0, stream>>>((float*)d_out, (float)ws_size);
    return;
  }

  float* ws = (float*)d_ws;
  float* h      = ws + OFF_H;
  u16* xnb      = (u16*)(ws + OFF_XNB);
  u16* BIG      = (u16*)(ws + OFF_BIG);
  u16* Vb       = (u16*)(ws + OFF_V);
  u16* WKPt     = (u16*)(ws + OFF_WKP);
  u16* WQPt     = (u16*)(ws + OFF_WQP);
  u16* WKt      = (u16*)(ws + OFF_WK);
  u16* WQt      = (u16*)(ws + OFF_WQ);
  u16* WVt      = (u16*)(ws + OFF_WV);
  u16* WOt      = (u16*)(ws + OFF_WO);
  u16* W1t      = (u16*)(ws + OFF_W1);
  u16* W2t      = (u16*)(ws + OFF_W2);
  u16* dg       = (u16*)(ws + OFF_DG);
  unsigned int* kmaxk = (unsigned int*)(ws + OFF_KMAX);
  float* part   = ws + OFF_PART;
  u16* Bt       = (u16*)(ws + OFF_PART);  // reuses part after ctxreduce (btprep reads ctx/ksum only)
  float* partk  = ws + OFF_PARTK;
  float* ctx    = ws + OFF_CTX;
  float* ksum   = ws + OFF_KSUM;
  float* pooled = ws + OFF_POOL;

  // ---- embed as MFMA GEMM ----
  xcvt_kernel<<<4096, 256, 0, stream>>>(x, BIG);
  wsplit_kernel<<<64, 256, 0, stream>>>(emb_w, WKPt, 64, 256, 8);
  mfma_gemm<4, 0, 0, 0, 2><<<dim3(512, 2), 256, 0, stream>>>(
      BIG, WKPt, nullptr, emb_b, pos, nullptr, h, nullptr, nullptr, nullptr, 256, 64);

  for (int l = 0; l < D_L; ++l) {
    const float* pj = proj + l * 2048;
    ln_kernel<<<TOK / 4, 256, 0, stream>>>(h, xnb, ln1_g + l * 256, ln1_b + l * 256);
    wprep_kernel<<<4096, 256, 0, stream>>>(
        wk + l * 65536, wq + l * 65536, wv + l * 65536, wo + l * 65536,
        w1 + l * 262144, w2 + l * 262144, pj,
        WKPt, WQPt, WKt, WQt, WVt, WOt, W1t, W2t, kmaxk);

    // fused xp(+kmax) and diag(k|q): one launch, y<4 xp / y>=4 diag
    mfma_gemm<6, 0, 0, 1, 1><<<dim3(512, 8), 256, 0, stream>>>(
        xnb, WKPt, WKt, nullptr, nullptr, nullptr, nullptr, BIG, dg, kmaxk, 512, 256);
    // context accumulation per half (exp fused into staging)
    for (int hf = 0; hf < 2; ++hf) {
      const u16* xh = xnb + (size_t)hf * 32768 * 256;
      mfma_gemm<0, 0, 0, 1, 1><<<dim3(256, 2), 256, 0, stream>>>(
          xh, WVt, nullptr, nullptr, nullptr, nullptr, nullptr, Vb, nullptr, nullptr, 256, 256);
      ctxaccum_kernel<<<dim3(32, 16), 256, 0, stream>>>(BIG, Vb, dg, kmaxk, part, partk, hf);
    }
    ctxreduce_kernel<<<64, 256, 0, stream>>>(part, partk, ctx, ksum);
    btprep_kernel<<<64, 256, 0, stream>>>(ctx, ksum, Bt);
    // qp (overwrites BIG; xp dead), single-plane WQP
    mfma_gemm<3, 0, 0, 1, 1><<<dim3(512, 4), 256, 0, stream>>>(
        xnb, WQPt, nullptr, nullptr, nullptr, dg, nullptr, BIG, nullptr, nullptr, 512, 256);
    for (int hf = 0; hf < 2; ++hf) {
      float* hh = h + (size_t)hf * 32768 * 256;
      attnout_kernel<<<dim3(256, 8), 256, 0, stream>>>(BIG, Bt, Vb, hf);
      mfma_gemm<0, 0, 1, 0, 1><<<dim3(256, 2), 256, 0, stream>>>(
          Vb, WOt, nullptr, bo + l * 256, nullptr, nullptr, hh, nullptr, nullptr, nullptr, 256, 256);
    }

    ln_kernel<<<TOK / 4, 256, 0, stream>>>(h, xnb, ln2_g + l * 256, ln2_b + l * 256);
    for (int hf = 0; hf < 2; ++hf) {
      const u16* xh = xnb + (size_t)hf * 32768 * 256;
      float* hh = h + (size_t)hf * 32768 * 256;
      // FFN single-plane bf16 (KM=1)
      mfma_gemm<0, 1, 0, 1, 1><<<dim3(256, 8), 256, 0, stream>>>(
          xh, W1t, nullptr, b1 + l * 1024, nullptr, nullptr, nullptr, BIG, nullptr, nullptr, 1024, 256);
      mfma_gemm<0, 0, 1, 0, 1><<<dim3(256, 2), 256, 0, stream>>>(
          BIG, W2t, nullptr, b2 + l * 256, nullptr, nullptr, hh, nullptr, nullptr, nullptr, 256, 1024);
    }
  }

  zero_kernel<<<8, 256, 0, stream>>>(pooled, 2048);
  pool_kernel<<<dim3(8, 32), 256, 0, stream>>>(h, pooled);
  final_kernel<<<1, 64, 0, stream>>>(pooled, fc_w, fc_b, (float*)d_out);
}

// Round 15
// 2089.189 us; speedup vs baseline: 1.0369x; 1.0096x over previous
//
#include <hip/hip_runtime.h>
#include <math.h>

typedef unsigned short u16;
typedef __attribute__((ext_vector_type(8))) short bf16x8;
typedef __attribute__((ext_vector_type(4))) float f32x4;

// ---- problem dims ----
static constexpr int D_S = 8192;
static constexpr int D_L = 4;
static constexpr int TOK = 65536;
static constexpr float NORMALIZER = 0.4204482076268573f;  // 32^-0.25
static constexpr float RATIO = 0.125f;                    // 64^-0.5
static constexpr float KEPS = 1e-4f;

// ---- workspace layout (float slots) ----
static constexpr size_t OFF_H     = 0;
static constexpr size_t OFF_XNB   = 16777216;
static constexpr size_t OFF_BIG   = 25165824;
static constexpr size_t OFF_V     = 41943040;
static constexpr size_t OFF_WKP   = 46137344;
static constexpr size_t OFF_WQP   = 46268416;
static constexpr size_t OFF_WK    = 46399488;
static constexpr size_t OFF_WQ    = 46465024;
static constexpr size_t OFF_WV    = 46530560;
static constexpr size_t OFF_WO    = 46596096;
static constexpr size_t OFF_W1    = 46661632;
static constexpr size_t OFF_W2    = 46923776;
static constexpr size_t OFF_DG    = 47185920;
static constexpr size_t OFF_KMAX  = 47710208;
static constexpr size_t OFF_PART  = 47710272;
static constexpr size_t OFF_PARTK = 49807424;
static constexpr size_t OFF_CTX   = 49872960;
static constexpr size_t OFF_KSUM  = 50004032;
static constexpr size_t OFF_POOL  = 50008128;
static constexpr size_t NEED_BYTES = 200040704;

static constexpr int BTS = 136;  // Bt row stride in u16 (128 + 8 pad)

static __device__ __forceinline__ float bf2f(u16 u) {
  return __uint_as_float(((unsigned int)u) << 16);
}
static __device__ __forceinline__ u16 f2bf(float f) {
  unsigned int u = __float_as_uint(f);
  u = (u + 0x7fffu + ((u >> 16) & 1u)) >> 16;
  return (u16)u;
}
static __device__ __forceinline__ float geluf(float v) {
  return 0.5f * v * (1.f + erff(v * 0.70710678118654752f));
}
static __device__ __forceinline__ float dec_max(unsigned int mk) {
  return __uint_as_float((mk & 0x80000000u) ? (mk & 0x7fffffffu) : ~mk);
}

// async global->LDS, 16B per lane; dest = wave-uniform base + lane*16 (m97 pattern)
static __device__ __forceinline__ void gload16(const u16* g, u16* l) {
  __builtin_amdgcn_global_load_lds(
      (const __attribute__((address_space(1))) unsigned int*)g,
      (__attribute__((address_space(3))) unsigned int*)l, 16, 0, 0);
}

__global__ void report_kernel(float* out, float v) {
  if (threadIdx.x < 16) out[threadIdx.x] = v;
}

__global__ __launch_bounds__(256) void zero_kernel(float* p, int n) {
  int i = blockIdx.x * 256 + threadIdx.x;
  if (i < n) p[i] = 0.f;
}

// ================= x -> bf16 =================
__global__ __launch_bounds__(256) void xcvt_kernel(const float* __restrict__ x,
                                                   u16* __restrict__ xb) {
  int i4 = (blockIdx.x * 256 + threadIdx.x) * 4;
  float4 v = *(const float4*)(x + i4);
  u16 o[4] = {f2bf(v.x), f2bf(v.y), f2bf(v.z), f2bf(v.w)};
  *(uint2*)(xb + i4) = *(uint2*)o;
}

// ================= layernorm: fp32 in, bf16 out =================
__global__ __launch_bounds__(256) void ln_kernel(
    const float* __restrict__ src, u16* __restrict__ dst,
    const float* __restrict__ g, const float* __restrict__ b) {
  int wv = threadIdx.x >> 6, lane = threadIdx.x & 63;
  int t = blockIdx.x * 4 + wv;
  const float4 v = *(const float4*)(src + (size_t)t * 256 + lane * 4);
  float s1 = v.x + v.y + v.z + v.w;
  float s2 = v.x * v.x + v.y * v.y + v.z * v.z + v.w * v.w;
  for (int off = 32; off; off >>= 1) {
    s1 += __shfl_xor(s1, off);
    s2 += __shfl_xor(s2, off);
  }
  float mu = s1 * (1.f / 256.f);
  float var = s2 * (1.f / 256.f) - mu * mu;
  float rs = rsqrtf(var + 1e-5f);
  float4 gg = *(const float4*)(g + lane * 4);
  float4 bb = *(const float4*)(b + lane * 4);
  u16 o0 = f2bf((v.x - mu) * rs * gg.x + bb.x);
  u16 o1 = f2bf((v.y - mu) * rs * gg.y + bb.y);
  u16 o2 = f2bf((v.z - mu) * rs * gg.z + bb.z);
  u16 o3 = f2bf((v.w - mu) * rs * gg.w + bb.w);
  uint2 pk;
  pk.x = (unsigned)o0 | ((unsigned)o1 << 16);
  pk.y = (unsigned)o2 | ((unsigned)o3 << 16);
  *(uint2*)(dst + (size_t)t * 256 + lane * 4) = pk;
}

// ===== embed weight split (hi/lo), used once pre-loop =====
__global__ __launch_bounds__(256) void wsplit_kernel(
    const float* __restrict__ W, u16* __restrict__ Wt, int K, int N, int nb) {
  int i = blockIdx.x * 256 + threadIdx.x;
  int k = i >> nb, n = i & (N - 1);
  float val = W[i];
  u16 hi = f2bf(val);
  u16 lo = f2bf(val - bf2f(hi));
  Wt[(size_t)n * 2 * K + k] = hi;
  Wt[(size_t)n * 2 * K + K + k] = lo;
}

// ===== merged per-layer weight prep (all single-plane except embed) =====
__global__ __launch_bounds__(256) void wprep_kernel(
    const float* __restrict__ wk, const float* __restrict__ wq,
    const float* __restrict__ wv, const float* __restrict__ wo,
    const float* __restrict__ w1, const float* __restrict__ w2,
    const float* __restrict__ proj,
    u16* __restrict__ WKP, u16* __restrict__ WQP,
    u16* __restrict__ WKt, u16* __restrict__ WQt,
    u16* __restrict__ WVt, u16* __restrict__ WOt,
    u16* __restrict__ W1t, u16* __restrict__ W2t,
    unsigned int* __restrict__ kmaxk) {
  int gi = blockIdx.x * 256 + threadIdx.x;
  if (gi < 64) kmaxk[gi] = 0u;
  if (gi < 262144) {  // WKP / WQP: proj-folded single-plane
    int i = gi & 131071;
    const float* w = (gi < 131072) ? wk : wq;
    u16* Wt = (gi < 131072) ? WKP : WQP;
    int k = i & 255, n = i >> 8;
    int head = n >> 6, m = n & 63;
    float s = 0.f;
#pragma unroll
    for (int d = 0; d < 32; ++d) s += w[k * 256 + head * 32 + d] * proj[m * 32 + d];
    Wt[(size_t)n * 256 + k] = f2bf(s * NORMALIZER);
  } else if (gi < 393216) {  // WKt / WQt single-plane
    int i = gi - 262144;
    const float* W = (i < 65536) ? wk : wq;
    u16* T = (i < 65536) ? WKt : WQt;
    int j = i & 65535;
    int k = j >> 8, n = j & 255;
    T[(size_t)n * 256 + k] = f2bf(W[j]);
  } else if (gi < 524288) {  // WVt / WOt single-plane
    int i = gi - 393216;
    const float* W = (i < 65536) ? wv : wo;
    u16* T = (i < 65536) ? WVt : WOt;
    int j = i & 65535;
    int k = j >> 8, n = j & 255;
    T[(size_t)n * 256 + k] = f2bf(W[j]);
  } else if (gi < 786432) {  // W1 single-plane: K=256, N=1024
    int i = gi - 524288;
    int k = i >> 10, n = i & 1023;
    W1t[(size_t)n * 256 + k] = f2bf(w1[i]);
  } else {                   // W2 single-plane: K=1024, N=256
    int i = gi - 786432;
    int k = i >> 8, n = i & 255;
    W2t[(size_t)n * 1024 + k] = f2bf(w2[i]);
  }
}

// ================= MFMA GEMM: 128x128 tile, A bf16 [M][K], Wt bf16 [N][K*KM] =================
// KM=2: hi/lo split weights; KM=1: single-plane.
// T1 XCD swizzle (bijective), y-fastest -> A-panel L2 reuse per XCD.
// Staging: gload_lds width=16, TRIPLE-buffered counted-vmcnt pipeline (T4, r6/r7 proven):
//   prologue stages 3 bufs (12 in flight); steady iter waits vmcnt(8), computes,
//   raw-barriers, stages t+3. Tail: vmcnt(4) -> vmcnt(0). Never drains mid-loop.
// T5: s_setprio(1) around the MFMA cluster (cross-block arbitration; r10 best).
// Chunk swizzle (both-sides, rule 21): LDS slot(row,q') = row*4 + q' holds global k-chunk
// q = q' ^ ((row>>1)&3); fragment reads same XOR -> 2-way bank (free, m136).
// EPI: 0 plain (ACT gelu, ACC fp32-acc, OBF bf16 store), 3 qp, 4 embed,
//      6 fused xp(y<4: store+max over Wt)+diag(y>=4: over Wt2)
template <int EPI, int ACT, int ACC, int OBF, int KM>
__global__ __launch_bounds__(256) void mfma_gemm(
    const u16* __restrict__ A, const u16* __restrict__ Wt,
    const u16* __restrict__ Wt2,
    const float* __restrict__ bias, const float* __restrict__ posP,
    const u16* __restrict__ diagIn,
    float* __restrict__ outF, u16* __restrict__ outB,
    u16* __restrict__ diagOut, unsigned int* __restrict__ kmaxOut,
    int N, int K) {
  __shared__ __align__(16) u16 Als[12288];  // 3 bufs x 512 slots x 8 u16 (24KB)
  __shared__ __align__(16) u16 Bls[12288];
  const int K2 = K * KM;
  int tid = threadIdx.x;
  // ---- T1 bijective XCD swizzle, y-fastest work order ----
  int tot = gridDim.x * gridDim.y;
  int f = blockIdx.x + gridDim.x * blockIdx.y;
  int wid = (f & 7) * (tot >> 3) + (f >> 3);
  int ny = gridDim.y;                       // power of 2 (2,4,8)
  int lg = 31 - __clz(ny);
  int xb = wid >> lg;
  int yb = wid & (ny - 1);
  int bm = xb * 128;
  const u16* Wp = Wt;
  int bn = yb * 128;
  if (EPI == 6 && yb >= 4) { Wp = Wt2; bn = (yb - 4) * 128; }
  int w = tid >> 6, lane = tid & 63;
  int wm = w >> 1, wn = w & 1;
  int lr = lane & 15, lq = lane >> 4;
  f32x4 acc[4][4];
#pragma unroll
  for (int i = 0; i < 4; ++i)
#pragma unroll
    for (int j = 0; j < 4; ++j) acc[i][j] = (f32x4){0.f, 0.f, 0.f, 0.f};
  // staging lane geometry (see header comment)
  int sub = lane >> 2;                         // row within 16-row group
  int qsw = (lane & 3) ^ ((lane >> 3) & 3);    // global k-chunk this lane fetches
  const u16* gA0 = A + (size_t)(bm + 32 * w + sub) * K + qsw * 8;
  const u16* gA1 = gA0 + (size_t)16 * K;
  const u16* gB0 = Wp + (size_t)(bn + 32 * w + sub) * K2 + qsw * 8;
  const u16* gB1 = gB0 + (size_t)16 * K2;
  u16* lA0 = Als + (w * 2 + 0) * 512;          // wave-uniform LDS bases (slot*8 u16)
  u16* lA1 = Als + (w * 2 + 1) * 512;
  u16* lB0 = Bls + (w * 2 + 0) * 512;
  u16* lB1 = Bls + (w * 2 + 1) * 512;
  // fragment read base (chunk swizzle folded in; per-lane constant)
  int qswr = lq ^ ((lr >> 1) & 3);
  int aB = wm * 256 + lr * 4 + qswr;
  int bB = wn * 256 + lr * 4 + qswr;

#define STAGE(buf, kk) do { \
    int ka_ = (kk) & (K - 1); int kb_ = (kk); int lo_ = (buf) * 4096; \
    gload16(gA0 + ka_, lA0 + lo_); \
    gload16(gA1 + ka_, lA1 + lo_); \
    gload16(gB0 + kb_, lB0 + lo_); \
    gload16(gB1 + kb_, lB1 + lo_); \
  } while (0)

  const int nt = K2 / 32;                      // >= 4 for all instantiations
  STAGE(0, 0);
  STAGE(1, 32);
  STAGE(2, 64);
  int cur = 0;
  for (int t = 0; t < nt; ++t) {
    if (t + 2 < nt)      asm volatile("s_waitcnt vmcnt(8)" ::: "memory");
    else if (t + 1 < nt) asm volatile("s_waitcnt vmcnt(4)" ::: "memory");
    else                 asm volatile("s_waitcnt vmcnt(0)" ::: "memory");
    __builtin_amdgcn_s_barrier();              // all waves' cur-buf loads landed
    __builtin_amdgcn_sched_barrier(0);         // pin: no ds_read above barrier1
    const bf16x8* Ab = (const bf16x8*)(Als + cur * 4096);
    const bf16x8* Bb = (const bf16x8*)(Bls + cur * 4096);
    bf16x8 af[4], bfr[4];
#pragma unroll
    for (int mi = 0; mi < 4; ++mi) af[mi] = Ab[aB + mi * 64];
#pragma unroll
    for (int ni = 0; ni < 4; ++ni) bfr[ni] = Bb[bB + ni * 64];
    __builtin_amdgcn_s_setprio(1);             // T5: favor MFMA-entering waves
#pragma unroll
    for (int mi = 0; mi < 4; ++mi)
#pragma unroll
      for (int ni = 0; ni < 4; ++ni)
        acc[mi][ni] = __builtin_amdgcn_mfma_f32_16x16x32_bf16(af[mi], bfr[ni], acc[mi][ni], 0, 0, 0);
    __builtin_amdgcn_s_setprio(0);
    asm volatile("s_waitcnt lgkmcnt(0)" ::: "memory");  // my ds_reads complete
    __builtin_amdgcn_sched_barrier(0);
    __builtin_amdgcn_s_barrier();              // all waves done reading cur buf
    __builtin_amdgcn_sched_barrier(0);         // pin: STAGE stays below barrier2
    if (t + 3 < nt) STAGE(cur, (t + 3) * 32);
    cur = (cur == 2) ? 0 : cur + 1;
  }
#undef STAGE
  // ---- epilogues ----  C/D: col = lane&15, row = (lane>>4)*4 + r  [m89-verified]
  if (EPI == 0) {
#pragma unroll
    for (int ni = 0; ni < 4; ++ni) {
      int col = bn + wn * 64 + ni * 16 + lr;
      float bv = bias ? bias[col] : 0.f;
#pragma unroll
      for (int mi = 0; mi < 4; ++mi)
#pragma unroll
        for (int rr = 0; rr < 4; ++rr) {
          int rowg = bm + wm * 64 + mi * 16 + lq * 4 + rr;
          float val = acc[mi][ni][rr] + bv;
          if (ACT) val = geluf(val);
          size_t o = (size_t)rowg * N + col;
          if (OBF) outB[o] = f2bf(val);
          else if (ACC) outF[o] += val;
          else outF[o] = val;
        }
    }
  }
  if (EPI == 3) {  // qp: in-wave row-max over the head's 64 cols, then exp; dg q-heads at +8
    int head = (bn + wn * 64) >> 6;
#pragma unroll
    for (int mi = 0; mi < 4; ++mi) {
      float rm[4] = {-3.4e38f, -3.4e38f, -3.4e38f, -3.4e38f};
#pragma unroll
      for (int ni = 0; ni < 4; ++ni)
#pragma unroll
        for (int rr = 0; rr < 4; ++rr) rm[rr] = fmaxf(rm[rr], acc[mi][ni][rr]);
#pragma unroll
      for (int rr = 0; rr < 4; ++rr) {
        float t = rm[rr];
        t = fmaxf(t, __shfl_xor(t, 1)); t = fmaxf(t, __shfl_xor(t, 2));
        t = fmaxf(t, __shfl_xor(t, 4)); t = fmaxf(t, __shfl_xor(t, 8));
        rm[rr] = t;
      }
#pragma unroll
      for (int rr = 0; rr < 4; ++rr) {
        int rowg = bm + wm * 64 + mi * 16 + lq * 4 + rr;
        float dgv = bf2f(diagIn[(size_t)rowg * 16 + 8 + head]);
#pragma unroll
        for (int ni = 0; ni < 4; ++ni) {
          int col = bn + wn * 64 + ni * 16 + lr;
          float v = RATIO * (__expf(acc[mi][ni][rr] - dgv - rm[rr]) + KEPS);
          outB[(size_t)rowg * N + col] = f2bf(v);
        }
      }
    }
  }
  if (EPI == 4) {  // embed: + bias + pos, fp32 store (N==256)
#pragma unroll
    for (int ni = 0; ni < 4; ++ni) {
      int col = bn + wn * 64 + ni * 16 + lr;
      float bv = bias[col];
#pragma unroll
      for (int mi = 0; mi < 4; ++mi)
#pragma unroll
        for (int rr = 0; rr < 4; ++rr) {
          int rowg = bm + wm * 64 + mi * 16 + lq * 4 + rr;
          outF[(size_t)rowg * 256 + col] =
              acc[mi][ni][rr] + bv + posP[(size_t)(rowg & (D_S - 1)) * 256 + col];
        }
    }
  }
  if (EPI == 6) {
    if (yb < 4) {  // xp: store bf16 + global max per (b, head)
      float mx = -3.4e38f;
#pragma unroll
      for (int mi = 0; mi < 4; ++mi)
#pragma unroll
        for (int ni = 0; ni < 4; ++ni)
#pragma unroll
          for (int rr = 0; rr < 4; ++rr) {
            float v = acc[mi][ni][rr];
            mx = fmaxf(mx, v);
            int rowg = bm + wm * 64 + mi * 16 + lq * 4 + rr;
            int col = bn + wn * 64 + ni * 16 + lr;
            outB[(size_t)rowg * N + col] = f2bf(v);
          }
#pragma unroll
      for (int off = 1; off < 64; off <<= 1) mx = fmaxf(mx, __shfl_xor(mx, off));
      if (lane == 0) {
        int b = bm >> 13;
        int head = (bn + wn * 64) >> 6;
        unsigned int u = __float_as_uint(mx);
        unsigned int key = (u & 0x80000000u) ? ~u : (u | 0x80000000u);
        atomicMax(kmaxOut + b * 8 + head, key);
      }
    } else {  // diag per head (32 cols); wave spans 2 heads; dg layout [t][16]
      const float c05n2 = 0.5f * NORMALIZER * NORMALIZER;
      int hb = (bn + wn * 64) >> 5;
#pragma unroll
      for (int mi = 0; mi < 4; ++mi) {
        float s0[4] = {0.f, 0.f, 0.f, 0.f}, s1[4] = {0.f, 0.f, 0.f, 0.f};
#pragma unroll
        for (int ni = 0; ni < 4; ++ni)
#pragma unroll
          for (int rr = 0; rr < 4; ++rr) {
            float v = acc[mi][ni][rr];
            if (ni < 2) s0[rr] += v * v; else s1[rr] += v * v;
          }
#pragma unroll
        for (int rr = 0; rr < 4; ++rr) {
          float a = s0[rr], b = s1[rr];
          a += __shfl_xor(a, 1); a += __shfl_xor(a, 2); a += __shfl_xor(a, 4); a += __shfl_xor(a, 8);
          b += __shfl_xor(b, 1); b += __shfl_xor(b, 2); b += __shfl_xor(b, 4); b += __shfl_xor(b, 8);
          if (lr == 0) {
            int rowg = bm + wm * 64 + mi * 16 + lq * 4 + rr;
            diagOut[(size_t)rowg * 16 + hb] = f2bf(c05n2 * a);
            diagOut[(size_t)rowg * 16 + hb + 1] = f2bf(c05n2 * b);
          }
        }
      }
    }
  }
}

// ===== ctxaccum: kp computed inline from raw xp (exp fused); part[m][e] = sum kp*v =====
__global__ __launch_bounds__(256) void ctxaccum_kernel(
    const u16* __restrict__ xp, const u16* __restrict__ v,
    const u16* __restrict__ dg, const unsigned int* __restrict__ kmaxk,
    float* __restrict__ part, float* __restrict__ partk, int hf) {
  __shared__ float kpS[64 * 64];
  __shared__ float vS[64 * 32];
  int tid = threadIdx.x;
  int bl = blockIdx.x >> 3, head = blockIdx.x & 7, c = blockIdx.y;
  int n0l = bl * 8192 + c * 512;   // within half (32768 tokens)
  int bhg = (hf * 4 + bl) * 8 + head;
  int tg0 = hf * 32768 + n0l;
  float mx = dec_max(kmaxk[bhg]);
  int m = tid & 63, eg = tid >> 6;
  float acc[8] = {};
  float ks = 0.f;
  const u16* kpb = xp + (size_t)tg0 * 512 + head * 64;
  const u16* vb = v + (size_t)n0l * 256 + head * 32;
  for (int tile = 0; tile < 8; ++tile) {
    int nb = tile * 64;
    __syncthreads();
#pragma unroll
    for (int i = 0; i < 2; ++i) {
      int idx8 = tid + i * 256;          // 512 chunks of 8
      int row = idx8 >> 3, c8 = (idx8 & 7) * 8;
      float dgrow = bf2f(dg[(size_t)(tg0 + nb + row) * 16 + head]);
      u16 tmp[8];
      *(uint4*)tmp = *(const uint4*)(kpb + (size_t)(nb + row) * 512 + c8);
#pragma unroll
      for (int j = 0; j < 8; ++j)
        kpS[row * 64 + c8 + j] = RATIO * (__expf(bf2f(tmp[j]) - dgrow - mx) + KEPS);
    }
    {
      int row = tid >> 2, c8 = (tid & 3) * 8;
      u16 tmp[8];
      *(uint4*)tmp = *(const uint4*)(vb + (size_t)(nb + row) * 256 + c8);
#pragma unroll
      for (int j = 0; j < 8; ++j) vS[row * 32 + c8 + j] = bf2f(tmp[j]);
    }
    __syncthreads();
#pragma unroll 4
    for (int n = 0; n < 64; ++n) {
      float kv = kpS[n * 64 + m];
      if (eg == 0) ks += kv;
      const float* vr = &vS[n * 32 + eg * 8];
#pragma unroll
      for (int j = 0; j < 8; ++j) acc[j] += kv * vr[j];
    }
  }
  float* pp = part + ((size_t)bhg * 16 + c) * 2048 + m * 32 + eg * 8;
#pragma unroll
  for (int j = 0; j < 8; ++j) pp[j] = acc[j];
  if (eg == 0) partk[((size_t)bhg * 16 + c) * 64 + m] = ks;
}

__global__ __launch_bounds__(256) void ctxreduce_kernel(
    const float* __restrict__ part, const float* __restrict__ partk,
    float* __restrict__ ctx, float* __restrict__ ksum) {
  int bh = blockIdx.x, tid = threadIdx.x;
#pragma unroll
  for (int i = 0; i < 8; ++i) {
    int idx = tid + i * 256;
    float s = 0.f;
#pragma unroll
    for (int cc = 0; cc < 16; ++cc)
      s += part[((size_t)bh * 16 + cc) * 2048 + idx];
    ctx[(size_t)bh * 2048 + idx] = s;
  }
  if (tid < 64) {
    float s = 0.f;
#pragma unroll
    for (int cc = 0; cc < 16; ++cc) s += partk[((size_t)bh * 16 + cc) * 64 + tid];
    ksum[bh * 64 + tid] = s;
  }
}

// ===== btprep: pack [ctx | ksum | 0] into B-operand hi/lo bf16: Bt[bh][48][BTS] =====
__global__ __launch_bounds__(256) void btprep_kernel(
    const float* __restrict__ ctx, const float* __restrict__ ksum,
    u16* __restrict__ Bt) {
  int bh = blockIdx.x, tid = threadIdx.x;
  for (int idx = tid; idx < 48 * 64; idx += 256) {
    int n = idx >> 6, k = idx & 63;
    float v = 0.f;
    if (n < 32) v = ctx[(size_t)bh * 2048 + k * 32 + n];
    else if (n == 32) v = ksum[bh * 64 + k];
    u16 hi = f2bf(v);
    u16 lo = f2bf(v - bf2f(hi));
    u16* row = Bt + ((size_t)bh * 48 + n) * BTS;
    row[k] = hi;
    row[64 + k] = lo;
  }
}

// ===== attnout via MFMA: ao = (qp@ctx)/(qp@ksum) =====
__global__ __launch_bounds__(256) void attnout_kernel(
    const u16* __restrict__ qp, const u16* __restrict__ Bt,
    u16* __restrict__ ao, int hf) {
  __shared__ __align__(16) u16 BtS[48 * BTS];
  int tid = threadIdx.x;
  int rb = blockIdx.x, head = blockIdx.y;
  int t0l = rb * 128;
  int bhg = ((hf * 32768 + t0l) >> 13) * 8 + head;
  {
    const uint4* src = (const uint4*)(Bt + (size_t)bhg * 48 * BTS);
    for (int i = tid; i < 48 * BTS / 8; i += 256) ((uint4*)BtS)[i] = src[i];
  }
  __syncthreads();
  int w = tid >> 6, lane = tid & 63;
  int lr = lane & 15, lq = lane >> 4;
  int tw = t0l + w * 32;
  const u16* qpb = qp + (size_t)(hf * 32768 + tw) * 512 + head * 64;
  bf16x8 af[2][2];
#pragma unroll
  for (int mt = 0; mt < 2; ++mt)
#pragma unroll
    for (int kc = 0; kc < 2; ++kc)
      af[mt][kc] = *(const bf16x8*)(qpb + (size_t)(mt * 16 + lr) * 512 + kc * 32 + lq * 8);
  f32x4 c0[2], c1[2], c2[2];
#pragma unroll
  for (int mt = 0; mt < 2; ++mt) {
    c0[mt] = (f32x4){0.f, 0.f, 0.f, 0.f};
    c1[mt] = (f32x4){0.f, 0.f, 0.f, 0.f};
    c2[mt] = (f32x4){0.f, 0.f, 0.f, 0.f};
  }
#pragma unroll
  for (int kc = 0; kc < 4; ++kc) {
    bf16x8 b0 = *(const bf16x8*)(BtS + (size_t)(0 * 16 + lr) * BTS + kc * 32 + lq * 8);
    bf16x8 b1 = *(const bf16x8*)(BtS + (size_t)(1 * 16 + lr) * BTS + kc * 32 + lq * 8);
    bf16x8 b2 = *(const bf16x8*)(BtS + (size_t)(2 * 16 + lr) * BTS + kc * 32 + lq * 8);
#pragma unroll
    for (int mt = 0; mt < 2; ++mt) {
      bf16x8 a = af[mt][kc & 1];
      c0[mt] = __builtin_amdgcn_mfma_f32_16x16x32_bf16(a, b0, c0[mt], 0, 0, 0);
      c1[mt] = __builtin_amdgcn_mfma_f32_16x16x32_bf16(a, b1, c1[mt], 0, 0, 0);
      c2[mt] = __builtin_amdgcn_mfma_f32_16x16x32_bf16(a, b2, c2[mt], 0, 0, 0);
    }
  }
#pragma unroll
  for (int mt = 0; mt < 2; ++mt)
#pragma unroll
    for (int rr = 0; rr < 4; ++rr) {
      float den = __shfl(c2[mt][rr], lane & 48);
      int rowl = tw + mt * 16 + lq * 4 + rr;
      float inv = 1.f / den;
      ao[(size_t)rowl * 256 + head * 32 + lr] = f2bf(c0[mt][rr] * inv);
      ao[(size_t)rowl * 256 + head * 32 + 16 + lr] = f2bf(c1[mt][rr] * inv);
    }
}

// ================= mean pool + final FC (fp32 h) =================
__global__ __launch_bounds__(256) void pool_kernel(
    const float* __restrict__ h, float* __restrict__ pooled) {
  int b = blockIdx.x, chunk = blockIdx.y, j = threadIdx.x;
  const float* hp = h + (size_t)(b * D_S + chunk * 256) * 256 + j;
  float acc = 0.f;
#pragma unroll 4
  for (int s = 0; s < 256; ++s) acc += hp[(size_t)s * 256];
  atomicAdd(pooled + b * 256 + j, acc);
}

__global__ __launch_bounds__(64) void final_kernel(
    const float* __restrict__ pooled, const float* __restrict__ fcw,
    const float* __restrict__ fcb, float* __restrict__ out) {
  int tid = threadIdx.x;
  if (tid >= 16) return;
  int b = tid >> 1, c = tid & 1;
  float acc = 0.f;
  for (int j = 0; j < 256; ++j) acc += pooled[b * 256 + j] * fcw[j * 2 + c];
  out[b * 2 + c] = acc * (1.f / 8192.f) + fcb[c];
}

extern "C" void kernel_launch(void* const* d_in, const int* in_sizes, int n_in,
                              void* d_out, int out_size, void* d_ws, size_t ws_size,
                              hipStream_t stream) {
  const float* x     = (const float*)d_in[0];
  const float* emb_w = (const float*)d_in[1];
  const float* emb_b = (const float*)d_in[2];
  const float* pos   = (const float*)d_in[3];
  const float* ln1_g = (const float*)d_in[4];
  const float* ln1_b = (const float*)d_in[5];
  const float* wq    = (const float*)d_in[6];
  const float* wk    = (const float*)d_in[7];
  const float* wv    = (const float*)d_in[8];
  const float* wo    = (const float*)d_in[9];
  const float* bo    = (const float*)d_in[10];
  const float* ln2_g = (const float*)d_in[11];
  const float* ln2_b = (const float*)d_in[12];
  const float* w1    = (const float*)d_in[13];
  const float* b1    = (const float*)d_in[14];
  const float* w2    = (const float*)d_in[15];
  const float* b2    = (const float*)d_in[16];
  const float* proj  = (const float*)d_in[17];
  const float* fc_w  = (const float*)d_in[18];
  const float* fc_b  = (const float*)d_in[19];

  if (ws_size < NEED_BYTES) {
    report_kernel<<<1, 64, 0, stream>>>((float*)d_out, (float)ws_size);
    return;
  }

  float* ws = (float*)d_ws;
  float* h      = ws + OFF_H;
  u16* xnb      = (u16*)(ws + OFF_XNB);
  u16* BIG      = (u16*)(ws + OFF_BIG);
  u16* Vb       = (u16*)(ws + OFF_V);
  u16* WKPt     = (u16*)(ws + OFF_WKP);
  u16* WQPt     = (u16*)(ws + OFF_WQP);
  u16* WKt      = (u16*)(ws + OFF_WK);
  u16* WQt      = (u16*)(ws + OFF_WQ);
  u16* WVt      = (u16*)(ws + OFF_WV);
  u16* WOt      = (u16*)(ws + OFF_WO);
  u16* W1t      = (u16*)(ws + OFF_W1);
  u16* W2t      = (u16*)(ws + OFF_W2);
  u16* dg       = (u16*)(ws + OFF_DG);
  unsigned int* kmaxk = (unsigned int*)(ws + OFF_KMAX);
  float* part   = ws + OFF_PART;
  u16* Bt       = (u16*)(ws + OFF_PART);  // reuses part after ctxreduce (btprep reads ctx/ksum only)
  float* partk  = ws + OFF_PARTK;
  float* ctx    = ws + OFF_CTX;
  float* ksum   = ws + OFF_KSUM;
  float* pooled = ws + OFF_POOL;

  // ---- embed as MFMA GEMM ----
  xcvt_kernel<<<4096, 256, 0, stream>>>(x, BIG);
  wsplit_kernel<<<64, 256, 0, stream>>>(emb_w, WKPt, 64, 256, 8);
  mfma_gemm<4, 0, 0, 0, 2><<<dim3(512, 2), 256, 0, stream>>>(
      BIG, WKPt, nullptr, emb_b, pos, nullptr, h, nullptr, nullptr, nullptr, 256, 64);

  for (int l = 0; l < D_L; ++l) {
    const float* pj = proj + l * 2048;
    ln_kernel<<<TOK / 4, 256, 0, stream>>>(h, xnb, ln1_g + l * 256, ln1_b + l * 256);
    wprep_kernel<<<4096, 256, 0, stream>>>(
        wk + l * 65536, wq + l * 65536, wv + l * 65536, wo + l * 65536,
        w1 + l * 262144, w2 + l * 262144, pj,
        WKPt, WQPt, WKt, WQt, WVt, WOt, W1t, W2t, kmaxk);

    // fused xp(+kmax) and diag(k|q): one launch, y<4 xp / y>=4 diag
    mfma_gemm<6, 0, 0, 1, 1><<<dim3(512, 8), 256, 0, stream>>>(
        xnb, WKPt, WKt, nullptr, nullptr, nullptr, nullptr, BIG, dg, kmaxk, 512, 256);
    // context accumulation per half (exp fused into staging)
    for (int hf = 0; hf < 2; ++hf) {
      const u16* xh = xnb + (size_t)hf * 32768 * 256;
      mfma_gemm<0, 0, 0, 1, 1><<<dim3(256, 2), 256, 0, stream>>>(
          xh, WVt, nullptr, nullptr, nullptr, nullptr, nullptr, Vb, nullptr, nullptr, 256, 256);
      ctxaccum_kernel<<<dim3(32, 16), 256, 0, stream>>>(BIG, Vb, dg, kmaxk, part, partk, hf);
    }
    ctxreduce_kernel<<<64, 256, 0, stream>>>(part, partk, ctx, ksum);
    btprep_kernel<<<64, 256, 0, stream>>>(ctx, ksum, Bt);
    // qp (overwrites BIG; xp dead), single-plane WQP
    mfma_gemm<3, 0, 0, 1, 1><<<dim3(512, 4), 256, 0, stream>>>(
        xnb, WQPt, nullptr, nullptr, nullptr, dg, nullptr, BIG, nullptr, nullptr, 512, 256);
    for (int hf = 0; hf < 2; ++hf) {
      float* hh = h + (size_t)hf * 32768 * 256;
      attnout_kernel<<<dim3(256, 8), 256, 0, stream>>>(BIG, Bt, Vb, hf);
      mfma_gemm<0, 0, 1, 0, 1><<<dim3(256, 2), 256, 0, stream>>>(
          Vb, WOt, nullptr, bo + l * 256, nullptr, nullptr, hh, nullptr, nullptr, nullptr, 256, 256);
    }

    ln_kernel<<<TOK / 4, 256, 0, stream>>>(h, xnb, ln2_g + l * 256, ln2_b + l * 256);
    for (int hf = 0; hf < 2; ++hf) {
      const u16* xh = xnb + (size_t)hf * 32768 * 256;
      float* hh = h + (size_t)hf * 32768 * 256;
      // FFN single-plane bf16 (KM=1)
      mfma_gemm<0, 1, 0, 1, 1><<<dim3(256, 8), 256, 0, stream>>>(
          xh, W1t, nullptr, b1 + l * 1024, nullptr, nullptr, nullptr, BIG, nullptr, nullptr, 1024, 256);
      mfma_gemm<0, 0, 1, 0, 1><<<dim3(256, 2), 256, 0, stream>>>(
          BIG, W2t, nullptr, b2 + l * 256, nullptr, nullptr, hh, nullptr, nullptr, nullptr, 256, 1024);
    }
  }

  zero_kernel<<<8, 256, 0, stream>>>(pooled, 2048);
  pool_kernel<<<dim3(8, 32), 256, 0, stream>>>(h, pooled);
  final_kernel<<<1, 64, 0, stream>>>(pooled, fc_w, fc_b, (float*)d_out);
}